// Round 1
// baseline (346.776 us; speedup 1.0000x reference)
//
#include <hip/hip_runtime.h>

#define NN 50000
#define FF 300
#define DD 128
#define HH 4
#define CC 32
#define EE 640000
#define RR 200
#define LL 2
#define SB ((NN + 255) / 256)     // scan blocks = 196
#define PK 320                    // proj K padded to multiple of 64
#define WCONV (2 * 128 * 128)     // layer-1 wl/wr transposed fp16
#define WTOT (2 * 128 * PK + WCONV)
#define HB ((EE + 255) / 256)     // hist blocks in prep (2500)
#define WB (WCONV / 256)          // wconv blocks (128)
#define FB PK                     // weight-fold blocks (320, 2 (lr,k) pairs each)
#define RB (LL * RR / 2)          // relproj blocks (200)

typedef unsigned short u16;
typedef unsigned int u32;
typedef _Float16 h2   __attribute__((ext_vector_type(2)));
typedef _Float16 half8 __attribute__((ext_vector_type(8)));  // MFMA A/B frag (4 VGPRs)
typedef __attribute__((ext_vector_type(4))) float floatx4;   // MFMA accumulator

__device__ __forceinline__ u16 f2h(float f) {
    union { _Float16 h; u16 u; } v; v.h = (_Float16)f; return v.u;
}
__device__ __forceinline__ float h2f(u16 u) {
    union { u16 u; _Float16 h; } v; v.u = u; return (float)v.h;
}
__device__ __forceinline__ h2 u2h2(u32 p) {
    union { u32 u; h2 h; } v; v.u = p; return v.h;
}
__device__ __forceinline__ h2 hmax2(h2 a, h2 b) {
#if __has_builtin(__builtin_elementwise_max)
    return __builtin_elementwise_max(a, b);
#else
    h2 r; r.x = a.x > b.x ? a.x : b.x; r.y = a.y > b.y ? a.y : b.y; return r;
#endif
}
__device__ __forceinline__ float hdot2(h2 a, h2 b, float c) {
#if __has_builtin(__builtin_amdgcn_fdot2)
    return __builtin_amdgcn_fdot2(a, b, c, false);
#else
    return c + (float)a.x * (float)b.x + (float)a.y * (float)b.y;
#endif
}

// block-wide (256 threads) scan: returns exclusive prefix of v; *total = block sum
__device__ __forceinline__ int block_excl_scan(int v, int* lds4, int* total) {
    int lane = threadIdx.x & 63, wid = threadIdx.x >> 6;
    int x = v;
    #pragma unroll
    for (int off = 1; off < 64; off <<= 1) {
        int y = __shfl_up(x, off, 64);
        if (lane >= off) x += y;
    }
    if (lane == 63) lds4[wid] = x;
    __syncthreads();
    int add = 0;
    #pragma unroll
    for (int w = 0; w < 4; w++) add += (w < wid) ? lds4[w] : 0;
    *total = lds4[0] + lds4[1] + lds4[2] + lds4[3];
    return x + add - v;
}

// ---------------- fused prep:
// hist | layer1 weight transpose-convert | layer0 proj-fold GEMM | bias-fold | relproj
__global__ __launch_bounds__(256)
void prep_kernel(const int* __restrict__ ei, int* __restrict__ counts,
                 const float* __restrict__ proj_w, const float* __restrict__ w_l,
                 const float* __restrict__ w_r, u16* __restrict__ wt,
                 const float* __restrict__ rel_emb, const float* __restrict__ w_e,
                 u16* __restrict__ erel, const float* __restrict__ proj_b,
                 const float* __restrict__ b_l, const float* __restrict__ b_r,
                 float* __restrict__ fbias)
{
    __shared__ float rv[2][DD];
    int b = blockIdx.x, tid = threadIdx.x;
    if (b < HB) {
        // degree histogram
        int e = b * 256 + tid;
        if (e < EE) atomicAdd(&counts[ei[EE + e]], 1);
    } else if (b < HB + WB) {
        // layer-1 weights: fp32 [k][n] -> fp16 wt[n][k], segs [wl1][wr1]
        int i = (b - HB) * 256 + tid;        // < 32768
        int seg = i >> 14;                   // 0 = wl1, 1 = wr1
        int r = i & 16383;
        int n = r >> 7, k = r & 127;
        const float* src = (seg == 0 ? w_l : w_r) + (size_t)DD * DD;  // layer 1
        wt[2 * 128 * PK + i] = f2h(src[(size_t)k * DD + n]);
    } else if (b < HB + WB + FB) {
        // fused layer-0 weights: F[k][n] = sum_j Wp[k][j]*W{l,r}0[j][n],
        // stored transposed fp16: wt[lr*128*PK + n*PK + k]  (k>=FF -> 0 pad)
        int half = tid >> 7, d = tid & 127;
        int pp = (b - HB - WB) * 2 + half;   // 0..639 = (lr,k)
        int lr = pp / PK, k = pp - lr * PK;
        rv[half][d] = (k < FF) ? proj_w[(size_t)k * DD + d] : 0.f;
        __syncthreads();
        float acc = 0.f;
        if (k < FF) {
            const float* W = lr ? w_r : w_l;             // layer 0
            #pragma unroll 8
            for (int j = 0; j < DD; j++) acc += rv[half][j] * W[(size_t)j * DD + d];
        }
        wt[(size_t)lr * 128 * PK + (size_t)d * PK + k] = f2h(acc);
    } else if (b == HB + WB + FB) {
        // fused layer-0 bias: fb = b_{l,r}0 + proj_b @ W{l,r}0  (fp32)
        int half = tid >> 7, d = tid & 127;
        if (tid < DD) rv[0][tid] = proj_b[tid];
        __syncthreads();
        const float* W = half ? w_r : w_l;
        float acc = half ? b_r[d] : b_l[d];
        #pragma unroll 8
        for (int j = 0; j < DD; j++) acc += rv[0][j] * W[(size_t)j * DD + d];
        fbias[half * DD + d] = acc;
    } else {
        // erel[l*RR+r][d] = rel_emb[r,:] @ w_e[l][:,d]   (2 lr per block, fp16 out)
        int half = tid >> 7, d = tid & 127;
        int lr = (b - HB - WB - FB - 1) * 2 + half;
        int l = lr / RR, r = lr - l * RR;
        rv[half][d] = rel_emb[r * DD + d];
        __syncthreads();
        const float* W = w_e + (size_t)l * DD * DD;
        float acc = 0.f;
        #pragma unroll 8
        for (int k = 0; k < DD; k++) acc += rv[half][k] * W[k * DD + d];
        erel[(size_t)lr * DD + d] = f2h(acc);
    }
}

// ---------------- dual-output MFMA fp16 GEMM, BK=64, tile 64 rows x 256 cols:
// C1[M,128] = A@BT1^T + bias1 ; C2[M,128] = A@BT2^T + bias2  (A staged ONCE)
template<bool AF16, bool GATHER>
__global__ __launch_bounds__(256)
void gemm_dual_kernel(const void* __restrict__ A_, const int* __restrict__ rowidx,
                      int lda, int K, int Ka, int ldb,
                      const u16* __restrict__ BT1, const float* __restrict__ bias1,
                      u16* __restrict__ C1,
                      const u16* __restrict__ BT2, const float* __restrict__ bias2,
                      u16* __restrict__ C2, int M)
{
    // pad 8 u16 -> 144 B rows (16B-aligned): same bank pattern as prior kernel
    __shared__ u16 As[64][72];
    __shared__ u16 Bs[256][72];   // rows 0-127 from BT1, 128-255 from BT2
    int tid  = threadIdx.x;
    int m0   = blockIdx.x * 64;
    int wave = tid >> 6, lane = tid & 63;
    int quad = lane >> 4, l16 = lane & 15;
    int wcol = wave * 64;          // wave covers cols [wcol, wcol+64)

    floatx4 acc[4][4];
    #pragma unroll
    for (int i = 0; i < 4; i++)
        #pragma unroll
        for (int j = 0; j < 4; j++) acc[i][j] = (floatx4){0.f, 0.f, 0.f, 0.f};

    int ar = tid >> 2, ak = (tid & 3) * 16;   // A: 64 rows x 4 threads, 16 halves each
    int arow = m0 + ar;
    int rid = (arow < M) ? (GATHER ? rowidx[arow] : arow) : 0;
    const u16* Brow = (tid < 128) ? (BT1 + (size_t)tid * ldb)
                                  : (BT2 + (size_t)(tid - 128) * ldb);

    for (int kk = 0; kk < K; kk += 64) {
        int kb = kk + ak;
        u16 tmp[16];
        if (AF16) {
            const u16* Ap = (const u16*)A_ + (size_t)rid * lda + kb;
            if (kb + 16 <= Ka) {
                *(half8*)&tmp[0] = *(const half8*)Ap;
                *(half8*)&tmp[8] = *(const half8*)(Ap + 8);
            } else {
                #pragma unroll
                for (int j = 0; j < 16; j++) tmp[j] = (kb + j < Ka) ? Ap[j] : (u16)0;
            }
        } else {
            const float* Ap = (const float*)A_ + (size_t)rid * lda + kb;
            if (kb + 16 <= Ka) {
                #pragma unroll
                for (int qq = 0; qq < 4; qq++) {
                    float4 f = *(const float4*)(Ap + qq * 4);
                    tmp[qq*4+0] = f2h(f.x); tmp[qq*4+1] = f2h(f.y);
                    tmp[qq*4+2] = f2h(f.z); tmp[qq*4+3] = f2h(f.w);
                }
            } else {
                #pragma unroll
                for (int j = 0; j < 16; j++) tmp[j] = (kb + j < Ka) ? f2h(Ap[j]) : (u16)0;
            }
        }
        *(half8*)&As[ar][ak]     = *(half8*)&tmp[0];
        *(half8*)&As[ar][ak + 8] = *(half8*)&tmp[8];
        // B staging: one row per thread, 64 halves (L2-resident, re-read per block)
        #pragma unroll
        for (int q = 0; q < 8; q++)
            *(half8*)&Bs[tid][q * 8] = *(const half8*)(Brow + kk + q * 8);
        __syncthreads();
        #pragma unroll
        for (int ks = 0; ks < 2; ks++) {
            half8 af[4], bf[4];
            #pragma unroll
            for (int i = 0; i < 4; i++)
                af[i] = *(const half8*)&As[i * 16 + l16][ks * 32 + quad * 8];
            #pragma unroll
            for (int j = 0; j < 4; j++)
                bf[j] = *(const half8*)&Bs[wcol + j * 16 + l16][ks * 32 + quad * 8];
            #pragma unroll
            for (int i = 0; i < 4; i++)
                #pragma unroll
                for (int j = 0; j < 4; j++)
                    acc[i][j] = __builtin_amdgcn_mfma_f32_16x16x32_f16(
                        af[i], bf[j], acc[i][j], 0, 0, 0);
        }
        __syncthreads();
    }

    // epilogue: C/D layout col=lane&15, row=quad*4+reg (m89; dtype-independent m121)
    // wave 0/1 -> C1 cols 0-127, wave 2/3 -> C2 cols 0-127 (uniform per wave)
    u16* Cw = (wave < 2) ? C1 : C2;
    const float* bw = (wave < 2) ? bias1 : bias2;
    int cbase = wcol & 127;
    #pragma unroll
    for (int i = 0; i < 4; i++) {
        #pragma unroll
        for (int rr = 0; rr < 4; rr++) {
            int row = m0 + i * 16 + quad * 4 + rr;
            if (row < M) {
                #pragma unroll
                for (int j = 0; j < 4; j++) {
                    int col = cbase + j * 16 + l16;
                    Cw[(size_t)row * DD + col] = f2h(acc[i][j][rr] + bw[col]);
                }
            }
        }
    }
}

// ---------------- CSR scan (two-level, add folded into consumers) + scatter
__global__ __launch_bounds__(256)
void scan_local_kernel(const int* __restrict__ counts, int* __restrict__ offsets,
                       int* __restrict__ bsum)
{
    __shared__ int lds4[4];
    int i = blockIdx.x * 256 + threadIdx.x;
    int v = (i < NN) ? counts[i] : 0;
    int total;
    int ex = block_excl_scan(v, lds4, &total);
    if (i < NN) offsets[i] = ex;
    if (threadIdx.x == 0) bsum[blockIdx.x] = total;
}

__global__ __launch_bounds__(256)
void scan_bsum_kernel(int* __restrict__ bsum)
{
    __shared__ int lds4[4];
    int t = threadIdx.x;
    int v = (t < SB) ? bsum[t] : 0;
    int total;
    int ex = block_excl_scan(v, lds4, &total);
    if (t < SB) bsum[t] = ex;
}

// one random 4B write per edge (src 16b | type 16b packed; N<65536, R<256)
__global__ __launch_bounds__(256)
void scatter_kernel(const int* __restrict__ ei, const int* __restrict__ et,
                    const int* __restrict__ offsets, const int* __restrict__ bsum,
                    int* __restrict__ fill, u32* __restrict__ dstorder)
{
    int e = blockIdx.x * 256 + threadIdx.x;
    if (e >= EE) return;
    int d = ei[EE + e];
    int pos = offsets[d] + bsum[d >> 8] + atomicAdd(&fill[d], 1);
    dstorder[pos] = (u32)ei[e] | ((u32)et[e] << 16);
}

// ---------------- fused per-node: logits + softmax (no-shift) + aggregate + bias + act
// one wave per dst node; 8 edge-slots of 8 lanes; lane owns 16 channels (c0=(lane&7)*16)
// 2-deep software pipeline: dstorder prefetched 2 iters ahead, xl/erel rows 1 ahead.
__global__ __launch_bounds__(256)
void node_kernel(const u32* __restrict__ dstorder, const int* __restrict__ offsets,
                 const int* __restrict__ bsum,
                 const u16* __restrict__ xl, const u16* __restrict__ xr,
                 const u16* __restrict__ erel, const float* __restrict__ att,
                 const float* __restrict__ bias,
                 u16* __restrict__ xnext, float* __restrict__ outp, int is_last)
{
    int tid  = threadIdx.x;
    int node = blockIdx.x * 4 + (tid >> 6);
    int lane = tid & 63;
    if (node >= NN) return;
    int g  = lane >> 3;          // edge slot (8)
    int gl = lane & 7;           // channel set
    int c0 = gl * 16;
    int beg = offsets[node] + bsum[node >> 8];
    int end = (node == NN - 1) ? EE : offsets[node + 1] + bsum[(node + 1) >> 8];

    // per-node constants (packed fp16); all 8 slots read the same xr row (broadcast)
    h2 xrh[8], atth[8];
    {
        const u32* xp = (const u32*)&xr[(size_t)node * DD + c0];
        #pragma unroll
        for (int q = 0; q < 8; q++) xrh[q] = u2h2(xp[q]);
        #pragma unroll
        for (int q = 0; q < 8; q++) {
            float2 av = *(const float2*)&att[c0 + q * 2];
            atth[q] = (h2){(_Float16)av.x, (_Float16)av.y};
        }
    }
    const h2 c02 = (h2){(_Float16)0.2f, (_Float16)0.2f};

    float s = 0.f;
    h2 a2[8];
    #pragma unroll
    for (int q = 0; q < 8; q++) a2[q] = (h2){(_Float16)0.f, (_Float16)0.f};

    // pipeline prologue
    int es = beg + g;
    u32 stB = (es + 8 < end) ? dstorder[es + 8] : 0u;
    h2 xhA[8], ehA[8];
    {
        u32 stA = (es < end) ? dstorder[es] : 0u;
        int src = stA & 0xffff, typ = stA >> 16;
        const u32* xp = (const u32*)&xl[(size_t)src * DD + c0];
        const u32* ep = (const u32*)&erel[(size_t)typ * DD + c0];
        #pragma unroll
        for (int q = 0; q < 8; q++) { xhA[q] = u2h2(xp[q]); ehA[q] = u2h2(ep[q]); }
    }

    for (int base = beg; base < end; base += 8) {
        // prefetch: dstorder for iter+2, gather rows for iter+1
        u32 stN = (base + 16 + g < end) ? dstorder[base + 16 + g] : 0u;
        h2 xhB[8], ehB[8];
        {
            int src = stB & 0xffff, typ = stB >> 16;
            const u32* xp = (const u32*)&xl[(size_t)src * DD + c0];
            const u32* ep = (const u32*)&erel[(size_t)typ * DD + c0];
            #pragma unroll
            for (int q = 0; q < 8; q++) { xhB[q] = u2h2(xp[q]); ehB[q] = u2h2(ep[q]); }
        }
        // compute current edge from prefetched regs (all pk fp16, fp32 dot acc)
        float p = 0.f;
        #pragma unroll
        for (int q = 0; q < 8; q++) {
            h2 m = (xhA[q] + xrh[q]) + ehA[q];   // v_pk_add_f16 x2
            m = hmax2(m, m * c02);               // leaky: pk_mul + pk_max
            p = hdot2(m, atth[q], p);            // v_dot2_f32_f16
        }
        // per-head logit: head = 32 ch = 2 lanes (16 ch each)
        p += __shfl_xor(p, 1, 64);
        bool valid = (base + g) < end;
        // softmax without max-shift: logits are O(1); clamp guards inf
        float w = valid ? __expf(fminf(p, 60.f)) : 0.f;
        s += w;
        h2 wh = (h2){(_Float16)w, (_Float16)w};
        #pragma unroll
        for (int q = 0; q < 8; q++) a2[q] += wh * xhA[q];   // v_pk_fma_f16
        // rotate pipeline
        #pragma unroll
        for (int q = 0; q < 8; q++) { xhA[q] = xhB[q]; ehA[q] = ehB[q]; }
        stB = stN;
    }

    // cross-slot reduction (slots processed disjoint edges) — fp32 for safety
    float a[16];
    #pragma unroll
    for (int q = 0; q < 8; q++) { a[q*2] = (float)a2[q].x; a[q*2+1] = (float)a2[q].y; }
    #pragma unroll
    for (int j = 0; j < 16; j++) {
        a[j] += __shfl_xor(a[j], 8, 64);
        a[j] += __shfl_xor(a[j], 16, 64);
        a[j] += __shfl_xor(a[j], 32, 64);
    }
    s += __shfl_xor(s, 8, 64);
    s += __shfl_xor(s, 16, 64);
    s += __shfl_xor(s, 32, 64);

    if (lane < 8) {
        int cc = lane * 16;
        float rh = 1.f / fmaxf(s, 1e-30f);
        float bv[16], v[16];
        #pragma unroll
        for (int qq = 0; qq < 4; qq++) {
            float4 bq = *(const float4*)&bias[cc + qq * 4];
            bv[qq*4+0] = bq.x; bv[qq*4+1] = bq.y; bv[qq*4+2] = bq.z; bv[qq*4+3] = bq.w;
        }
        #pragma unroll
        for (int j = 0; j < 16; j++) v[j] = a[j] * rh + bv[j];
        if (is_last) {
            float4* op = (float4*)&outp[(size_t)node * DD + cc];
            #pragma unroll
            for (int qq = 0; qq < 4; qq++)
                op[qq] = make_float4(v[qq*4+0], v[qq*4+1], v[qq*4+2], v[qq*4+3]);
        } else {
            u16 pk[16];
            #pragma unroll
            for (int j = 0; j < 16; j++) {
                float w2 = v[j] > 0.f ? v[j] : __expf(v[j]) - 1.f;   // elu
                pk[j] = f2h(w2);
            }
            *(half8*)&xnext[(size_t)node * DD + cc]     = *(half8*)&pk[0];
            *(half8*)&xnext[(size_t)node * DD + cc + 8] = *(half8*)&pk[8];
        }
    }
}

extern "C" void kernel_launch(void* const* d_in, const int* in_sizes, int n_in,
                              void* d_out, int out_size, void* d_ws, size_t ws_size,
                              hipStream_t stream)
{
    const int*   entity        = (const int*)d_in[0];
    const int*   edge_index    = (const int*)d_in[1];
    const int*   edge_type     = (const int*)d_in[2];
    const float* node_features = (const float*)d_in[3];
    const float* rel_emb       = (const float*)d_in[4];
    const float* proj_w        = (const float*)d_in[5];
    const float* proj_b        = (const float*)d_in[6];
    const float* w_l           = (const float*)d_in[7];
    const float* b_l           = (const float*)d_in[8];
    const float* w_r           = (const float*)d_in[9];
    const float* b_r           = (const float*)d_in[10];
    const float* w_e           = (const float*)d_in[11];
    const float* att           = (const float*)d_in[12];
    const float* bias          = (const float*)d_in[13];

    // workspace (~42 MB), all fp16 tensors in u16 containers:
    u16*   xb      = (u16*)d_ws;                           // NN*DD (layer-0 output / layer-1 input)
    u16*   xl      = xb + (size_t)NN * DD;                 // NN*DD
    u16*   xr      = xl + (size_t)NN * DD;                 // NN*DD
    u16*   erel    = xr + (size_t)NN * DD;                 // LL*RR*DD
    u16*   wt      = erel + (size_t)LL * RR * DD;          // WTOT: [fusedL][fusedR][wl1][wr1]
    u32*   dstorder= (u32*)(wt + WTOT);                    // EE u32 (src|type, dst-order)
    int*   counts  = (int*)(dstorder + (size_t)EE);        // NN int
    int*   fill    = counts + NN;                          // NN int
    int*   offsets = fill + NN;                            // NN int (local scans)
    int*   bsum    = offsets + NN;                         // SB int
    float* fbias   = (float*)(bsum + SB);                  // 256 fp32 (folded layer-0 bias)

    // ---- prep: zero counts+fill, then fused hist | wconv | fold | biasfold | relproj
    hipMemsetAsync(counts, 0, (size_t)NN * 2 * sizeof(int), stream);
    prep_kernel<<<HB + WB + FB + 1 + RB, 256, 0, stream>>>(
        edge_index, counts, proj_w, w_l, w_r, wt, rel_emb, w_e, erel,
        proj_b, b_l, b_r, fbias);

    // ---- CSR: two-level scan + packed scatter (edges constant across layers)
    scan_local_kernel<<<SB, 256, 0, stream>>>(counts, offsets, bsum);
    scan_bsum_kernel<<<1, 256, 0, stream>>>(bsum);
    scatter_kernel<<<(EE + 255) / 256, 256, 0, stream>>>(
        edge_index, edge_type, offsets, bsum, fill, dstorder);

    const int GB2 = (NN + 63) / 64;

    // ---- layer 0: proj folded into xl/xr — single GEMM reads node_features once
    gemm_dual_kernel<false, true><<<GB2, 256, 0, stream>>>(
        node_features, entity, FF, PK, FF, PK,
        wt, fbias, xl,
        wt + (size_t)128 * PK, fbias + DD, xr, NN);
    node_kernel<<<(NN + 3) / 4, 256, 0, stream>>>(
        dstorder, offsets, bsum, xl, xr, erel,
        att, bias, xb, (float*)d_out, 0);

    // ---- layer 1: dual-output GEMM reads xb once
    gemm_dual_kernel<true, false><<<GB2, 256, 0, stream>>>(
        xb, nullptr, DD, DD, DD, DD,
        wt + (size_t)2 * 128 * PK, b_l + DD, xl,
        wt + (size_t)2 * 128 * PK + 128 * 128, b_r + DD, xr, NN);
    node_kernel<<<(NN + 3) / 4, 256, 0, stream>>>(
        dstorder, offsets, bsum, xl, xr, erel + (size_t)RR * DD,
        att + DD, bias + DD, xb, (float*)d_out, 1);
}

// Round 2
// 330.362 us; speedup vs baseline: 1.0497x; 1.0497x over previous
//
#include <hip/hip_runtime.h>

#define NN 50000
#define FF 300
#define DD 128
#define HH 4
#define CC 32
#define EE 640000
#define RR 200
#define LL 2
#define SB ((NN + 255) / 256)     // scan blocks = 196
#define PK 320                    // proj K padded to multiple of 64
#define WCONV (2 * 128 * 128)     // layer-1 wl/wr transposed fp16
#define WTOT (2 * 128 * PK + WCONV)
#define HB ((EE + 255) / 256)     // hist blocks in prep (2500)
#define WB (WCONV / 256)          // wconv blocks (128)
#define FB PK                     // weight-fold blocks (320, 2 (lr,k) pairs each)
#define RB (LL * RR / 2)          // relproj blocks (200)

typedef unsigned short u16;
typedef unsigned int u32;
typedef _Float16 h2   __attribute__((ext_vector_type(2)));
typedef _Float16 half8 __attribute__((ext_vector_type(8)));  // MFMA A/B frag (4 VGPRs)
typedef __attribute__((ext_vector_type(4))) float floatx4;   // MFMA accumulator

__device__ __forceinline__ u16 f2h(float f) {
    union { _Float16 h; u16 u; } v; v.h = (_Float16)f; return v.u;
}
__device__ __forceinline__ float h2f(u16 u) {
    union { u16 u; _Float16 h; } v; v.u = u; return (float)v.h;
}
__device__ __forceinline__ h2 u2h2(u32 p) {
    union { u32 u; h2 h; } v; v.u = p; return v.h;
}
__device__ __forceinline__ h2 hmax2(h2 a, h2 b) {
#if __has_builtin(__builtin_elementwise_max)
    return __builtin_elementwise_max(a, b);
#else
    h2 r; r.x = a.x > b.x ? a.x : b.x; r.y = a.y > b.y ? a.y : b.y; return r;
#endif
}
__device__ __forceinline__ float hdot2(h2 a, h2 b, float c) {
#if __has_builtin(__builtin_amdgcn_fdot2)
    return __builtin_amdgcn_fdot2(a, b, c, false);
#else
    return c + (float)a.x * (float)b.x + (float)a.y * (float)b.y;
#endif
}

// block-wide (256 threads) scan: returns exclusive prefix of v; *total = block sum
__device__ __forceinline__ int block_excl_scan(int v, int* lds4, int* total) {
    int lane = threadIdx.x & 63, wid = threadIdx.x >> 6;
    int x = v;
    #pragma unroll
    for (int off = 1; off < 64; off <<= 1) {
        int y = __shfl_up(x, off, 64);
        if (lane >= off) x += y;
    }
    if (lane == 63) lds4[wid] = x;
    __syncthreads();
    int add = 0;
    #pragma unroll
    for (int w = 0; w < 4; w++) add += (w < wid) ? lds4[w] : 0;
    *total = lds4[0] + lds4[1] + lds4[2] + lds4[3];
    return x + add - v;
}

// ---------------- fused prep:
// hist | layer1 weight transpose-convert | layer0 proj-fold GEMM | bias-fold | relproj
__global__ __launch_bounds__(256)
void prep_kernel(const int* __restrict__ ei, int* __restrict__ counts,
                 const float* __restrict__ proj_w, const float* __restrict__ w_l,
                 const float* __restrict__ w_r, u16* __restrict__ wt,
                 const float* __restrict__ rel_emb, const float* __restrict__ w_e,
                 u16* __restrict__ erel, const float* __restrict__ proj_b,
                 const float* __restrict__ b_l, const float* __restrict__ b_r,
                 float* __restrict__ fbias)
{
    __shared__ float rv[2][DD];
    int b = blockIdx.x, tid = threadIdx.x;
    if (b < HB) {
        // degree histogram
        int e = b * 256 + tid;
        if (e < EE) atomicAdd(&counts[ei[EE + e]], 1);
    } else if (b < HB + WB) {
        // layer-1 weights: fp32 [k][n] -> fp16 wt[n][k], segs [wl1][wr1]
        int i = (b - HB) * 256 + tid;        // < 32768
        int seg = i >> 14;                   // 0 = wl1, 1 = wr1
        int r = i & 16383;
        int n = r >> 7, k = r & 127;
        const float* src = (seg == 0 ? w_l : w_r) + (size_t)DD * DD;  // layer 1
        wt[2 * 128 * PK + i] = f2h(src[(size_t)k * DD + n]);
    } else if (b < HB + WB + FB) {
        // fused layer-0 weights: F[k][n] = sum_j Wp[k][j]*W{l,r}0[j][n],
        // stored transposed fp16: wt[lr*128*PK + n*PK + k]  (k>=FF -> 0 pad)
        int half = tid >> 7, d = tid & 127;
        int pp = (b - HB - WB) * 2 + half;   // 0..639 = (lr,k)
        int lr = pp / PK, k = pp - lr * PK;
        rv[half][d] = (k < FF) ? proj_w[(size_t)k * DD + d] : 0.f;
        __syncthreads();
        float acc = 0.f;
        if (k < FF) {
            const float* W = lr ? w_r : w_l;             // layer 0
            #pragma unroll 8
            for (int j = 0; j < DD; j++) acc += rv[half][j] * W[(size_t)j * DD + d];
        }
        wt[(size_t)lr * 128 * PK + (size_t)d * PK + k] = f2h(acc);
    } else if (b == HB + WB + FB) {
        // fused layer-0 bias: fb = b_{l,r}0 + proj_b @ W{l,r}0  (fp32)
        int half = tid >> 7, d = tid & 127;
        if (tid < DD) rv[0][tid] = proj_b[tid];
        __syncthreads();
        const float* W = half ? w_r : w_l;
        float acc = half ? b_r[d] : b_l[d];
        #pragma unroll 8
        for (int j = 0; j < DD; j++) acc += rv[0][j] * W[(size_t)j * DD + d];
        fbias[half * DD + d] = acc;
    } else {
        // erel[l*RR+r][d] = rel_emb[r,:] @ w_e[l][:,d]   (2 lr per block, fp16 out)
        int half = tid >> 7, d = tid & 127;
        int lr = (b - HB - WB - FB - 1) * 2 + half;
        int l = lr / RR, r = lr - l * RR;
        rv[half][d] = rel_emb[r * DD + d];
        __syncthreads();
        const float* W = w_e + (size_t)l * DD * DD;
        float acc = 0.f;
        #pragma unroll 8
        for (int k = 0; k < DD; k++) acc += rv[half][k] * W[k * DD + d];
        erel[(size_t)lr * DD + d] = f2h(acc);
    }
}

// ---------------- dual-output MFMA fp16 GEMM, tile 64 rows x 256 cols (both outputs).
// A staged once via LDS (coalesced); B fragments loaded DIRECTLY from L2 into regs
// (B is 40-160 KB total, L2-resident; 8 contiguous halves per lane per fragment).
// No Bs LDS -> no bank conflicts, barrier protects only the 9 KB A tile.
template<bool AF16, bool GATHER, int K>
__global__ __launch_bounds__(256)
void gemm_bdirect_kernel(const void* __restrict__ A_, const int* __restrict__ rowidx,
                         int lda, int Ka,
                         const u16* __restrict__ BT1, const float* __restrict__ bias1,
                         u16* __restrict__ C1,
                         const u16* __restrict__ BT2, const float* __restrict__ bias2,
                         u16* __restrict__ C2, int M)
{
    __shared__ u16 As[64][72];    // 144 B rows: 2-way bank aliasing only (free, m136)
    int tid  = threadIdx.x;
    int m0   = blockIdx.x * 64;
    int wave = tid >> 6, lane = tid & 63;
    int quad = lane >> 4, l16 = lane & 15;
    // wave 0/1 -> C1 cols 0-63 / 64-127 ; wave 2/3 -> C2 cols 0-63 / 64-127
    const u16* BT = (wave < 2) ? BT1 : BT2;
    int wcol = (wave & 1) * 64;

    floatx4 acc[4][4];
    #pragma unroll
    for (int i = 0; i < 4; i++)
        #pragma unroll
        for (int j = 0; j < 4; j++) acc[i][j] = (floatx4){0.f, 0.f, 0.f, 0.f};

    // per-lane B row pointers (rows are MFMA cols); ldb == K for both weight blocks
    const u16* Brow[4];
    #pragma unroll
    for (int j = 0; j < 4; j++) Brow[j] = BT + (size_t)(wcol + j * 16 + l16) * K;

    int ar = tid >> 2, ak = (tid & 3) * 16;   // A: 64 rows x 4 threads, 16 halves each
    int arow = m0 + ar;
    int rid = (arow < M) ? (GATHER ? rowidx[arow] : arow) : 0;

    #pragma unroll
    for (int kk = 0; kk < K; kk += 64) {
        int kb = kk + ak;
        u16 tmp[16];
        if (AF16) {
            const u16* Ap = (const u16*)A_ + (size_t)rid * lda + kb;
            *(half8*)&tmp[0] = *(const half8*)Ap;
            *(half8*)&tmp[8] = *(const half8*)(Ap + 8);
        } else {
            const float* Ap = (const float*)A_ + (size_t)rid * lda + kb;
            if (kb + 16 <= Ka) {
                #pragma unroll
                for (int qq = 0; qq < 4; qq++) {
                    float4 f = *(const float4*)(Ap + qq * 4);
                    tmp[qq*4+0] = f2h(f.x); tmp[qq*4+1] = f2h(f.y);
                    tmp[qq*4+2] = f2h(f.z); tmp[qq*4+3] = f2h(f.w);
                }
            } else {
                #pragma unroll
                for (int j = 0; j < 16; j++) tmp[j] = (kb + j < Ka) ? f2h(Ap[j]) : (u16)0;
            }
        }
        *(half8*)&As[ar][ak]     = *(half8*)&tmp[0];
        *(half8*)&As[ar][ak + 8] = *(half8*)&tmp[8];
        __syncthreads();
        #pragma unroll
        for (int ks = 0; ks < 2; ks++) {
            half8 af[4], bf[4];
            #pragma unroll
            for (int i = 0; i < 4; i++)
                af[i] = *(const half8*)&As[i * 16 + l16][ks * 32 + quad * 8];
            #pragma unroll
            for (int j = 0; j < 4; j++)
                bf[j] = *(const half8*)(Brow[j] + kk + ks * 32 + quad * 8);
            #pragma unroll
            for (int i = 0; i < 4; i++)
                #pragma unroll
                for (int j = 0; j < 4; j++)
                    acc[i][j] = __builtin_amdgcn_mfma_f32_16x16x32_f16(
                        af[i], bf[j], acc[i][j], 0, 0, 0);
        }
        __syncthreads();
    }

    // epilogue: C/D layout col=lane&15, row=quad*4+reg (m89; dtype-independent m121)
    u16* Cw = (wave < 2) ? C1 : C2;
    const float* bw = (wave < 2) ? bias1 : bias2;
    #pragma unroll
    for (int i = 0; i < 4; i++) {
        #pragma unroll
        for (int rr = 0; rr < 4; rr++) {
            int row = m0 + i * 16 + quad * 4 + rr;
            if (row < M) {
                #pragma unroll
                for (int j = 0; j < 4; j++) {
                    int col = wcol + j * 16 + l16;
                    Cw[(size_t)row * DD + col] = f2h(acc[i][j][rr] + bw[col]);
                }
            }
        }
    }
}

// ---------------- CSR scan (two-level, add folded into consumers) + scatter
__global__ __launch_bounds__(256)
void scan_local_kernel(const int* __restrict__ counts, int* __restrict__ offsets,
                       int* __restrict__ bsum)
{
    __shared__ int lds4[4];
    int i = blockIdx.x * 256 + threadIdx.x;
    int v = (i < NN) ? counts[i] : 0;
    int total;
    int ex = block_excl_scan(v, lds4, &total);
    if (i < NN) offsets[i] = ex;
    if (threadIdx.x == 0) bsum[blockIdx.x] = total;
}

__global__ __launch_bounds__(256)
void scan_bsum_kernel(int* __restrict__ bsum)
{
    __shared__ int lds4[4];
    int t = threadIdx.x;
    int v = (t < SB) ? bsum[t] : 0;
    int total;
    int ex = block_excl_scan(v, lds4, &total);
    if (t < SB) bsum[t] = ex;
}

// one random 4B write per edge (src 16b | type 16b packed; N<65536, R<256)
__global__ __launch_bounds__(256)
void scatter_kernel(const int* __restrict__ ei, const int* __restrict__ et,
                    const int* __restrict__ offsets, const int* __restrict__ bsum,
                    int* __restrict__ fill, u32* __restrict__ dstorder)
{
    int e = blockIdx.x * 256 + threadIdx.x;
    if (e >= EE) return;
    int d = ei[EE + e];
    int pos = offsets[d] + bsum[d >> 8] + atomicAdd(&fill[d], 1);
    dstorder[pos] = (u32)ei[e] | ((u32)et[e] << 16);
}

// ---------------- fused per-node: logits + softmax (no-shift) + aggregate + bias + act
// one wave per dst node; 4 edge-groups of 16 lanes; lane owns 8 channels (c0=(lane&15)*8)
// ALL fp16-packed math in the hot loop: pk_add/pk_max/fdot2/pk_fma, zero unpacks.
__global__ __launch_bounds__(256)
void node_kernel(const u32* __restrict__ dstorder, const int* __restrict__ offsets,
                 const int* __restrict__ bsum,
                 const u16* __restrict__ xl, const u16* __restrict__ xr,
                 const u16* __restrict__ erel, const float* __restrict__ att,
                 const float* __restrict__ bias,
                 u16* __restrict__ xnext, float* __restrict__ outp, int is_last)
{
    int tid  = threadIdx.x;
    int node = blockIdx.x * 4 + (tid >> 6);
    int lane = tid & 63;
    if (node >= NN) return;
    int g  = lane >> 4;          // edge slot within quad
    int gl = lane & 15;          // channel set
    int c0 = gl * 8;
    int beg = offsets[node] + bsum[node >> 8];
    int end = (node == NN - 1) ? EE : offsets[node + 1] + bsum[(node + 1) >> 8];

    // per-node constants (packed fp16)
    h2 xrh[4], atth[4];
    {
        const u32* xp = (const u32*)&xr[(size_t)node * DD + c0];
        #pragma unroll
        for (int q = 0; q < 4; q++) xrh[q] = u2h2(xp[q]);
        #pragma unroll
        for (int q = 0; q < 4; q++) {
            float2 av = *(const float2*)&att[c0 + q * 2];
            atth[q] = (h2){(_Float16)av.x, (_Float16)av.y};
        }
    }
    const h2 c02 = (h2){(_Float16)0.2f, (_Float16)0.2f};

    float s = 0.f;
    h2 a2[4];
    #pragma unroll
    for (int q = 0; q < 4; q++) a2[q] = (h2){(_Float16)0.f, (_Float16)0.f};

    for (int base = beg; base < end; base += 4) {
        int es = base + g;
        bool valid = es < end;
        u32 st = valid ? dstorder[es] : 0;
        int src = st & 0xffff;
        int typ = st >> 16;
        const u32* xp = (const u32*)&xl[(size_t)src * DD + c0];
        const u32* ep = (const u32*)&erel[(size_t)typ * DD + c0];
        h2 xh[4];
        float p = 0.f;
        #pragma unroll
        for (int q = 0; q < 4; q++) {
            xh[q] = u2h2(xp[q]);
            h2 m = (xh[q] + xrh[q]) + u2h2(ep[q]);   // v_pk_add_f16 x2
            m = hmax2(m, m * c02);                   // leaky: pk_mul + pk_max
            p = hdot2(m, atth[q], p);                // v_dot2_f32_f16 (fp32 acc)
        }
        // per-head logit: reduce over the 4 lanes of this head (gl span of 4)
        p += __shfl_xor(p, 1, 64);
        p += __shfl_xor(p, 2, 64);
        // softmax without max-shift: logits are O(1); clamp guards inf
        float w = valid ? __expf(fminf(p, 60.f)) : 0.f;
        s += w;
        h2 wh = (h2){(_Float16)w, (_Float16)w};
        #pragma unroll
        for (int q = 0; q < 4; q++) a2[q] += wh * xh[q];   // v_pk_fma_f16
    }

    // cross-group reduction (groups processed disjoint edges) — fp32 for safety
    float a[8];
    #pragma unroll
    for (int q = 0; q < 4; q++) { a[q*2] = (float)a2[q].x; a[q*2+1] = (float)a2[q].y; }
    #pragma unroll
    for (int j = 0; j < 8; j++) {
        a[j] += __shfl_xor(a[j], 16, 64);
        a[j] += __shfl_xor(a[j], 32, 64);
    }
    s += __shfl_xor(s, 16, 64);
    s += __shfl_xor(s, 32, 64);

    if (lane < 16) {
        float rh = 1.f / fmaxf(s, 1e-30f);
        float4 b0 = *(const float4*)&bias[c0];
        float4 b1 = *(const float4*)&bias[c0 + 4];
        float bv[8] = {b0.x, b0.y, b0.z, b0.w, b1.x, b1.y, b1.z, b1.w};
        float v[8];
        #pragma unroll
        for (int j = 0; j < 8; j++) v[j] = a[j] * rh + bv[j];
        if (is_last) {
            float4* op = (float4*)&outp[(size_t)node * DD + c0];
            op[0] = make_float4(v[0], v[1], v[2], v[3]);
            op[1] = make_float4(v[4], v[5], v[6], v[7]);
        } else {
            u16 pk[8];
            #pragma unroll
            for (int j = 0; j < 8; j++) {
                float w2 = v[j] > 0.f ? v[j] : __expf(v[j]) - 1.f;   // elu
                pk[j] = f2h(w2);
            }
            *(half8*)&xnext[(size_t)node * DD + c0] = *(half8*)pk;
        }
    }
}

extern "C" void kernel_launch(void* const* d_in, const int* in_sizes, int n_in,
                              void* d_out, int out_size, void* d_ws, size_t ws_size,
                              hipStream_t stream)
{
    const int*   entity        = (const int*)d_in[0];
    const int*   edge_index    = (const int*)d_in[1];
    const int*   edge_type     = (const int*)d_in[2];
    const float* node_features = (const float*)d_in[3];
    const float* rel_emb       = (const float*)d_in[4];
    const float* proj_w        = (const float*)d_in[5];
    const float* proj_b        = (const float*)d_in[6];
    const float* w_l           = (const float*)d_in[7];
    const float* b_l           = (const float*)d_in[8];
    const float* w_r           = (const float*)d_in[9];
    const float* b_r           = (const float*)d_in[10];
    const float* w_e           = (const float*)d_in[11];
    const float* att           = (const float*)d_in[12];
    const float* bias          = (const float*)d_in[13];

    // workspace (~42 MB), all fp16 tensors in u16 containers:
    u16*   xb      = (u16*)d_ws;                           // NN*DD (layer-0 output / layer-1 input)
    u16*   xl      = xb + (size_t)NN * DD;                 // NN*DD
    u16*   xr      = xl + (size_t)NN * DD;                 // NN*DD
    u16*   erel    = xr + (size_t)NN * DD;                 // LL*RR*DD
    u16*   wt      = erel + (size_t)LL * RR * DD;          // WTOT: [fusedL][fusedR][wl1][wr1]
    u32*   dstorder= (u32*)(wt + WTOT);                    // EE u32 (src|type, dst-order)
    int*   counts  = (int*)(dstorder + (size_t)EE);        // NN int
    int*   fill    = counts + NN;                          // NN int
    int*   offsets = fill + NN;                            // NN int (local scans)
    int*   bsum    = offsets + NN;                         // SB int
    float* fbias   = (float*)(bsum + SB);                  // 256 fp32 (folded layer-0 bias)

    // ---- prep: zero counts+fill, then fused hist | wconv | fold | biasfold | relproj
    hipMemsetAsync(counts, 0, (size_t)NN * 2 * sizeof(int), stream);
    prep_kernel<<<HB + WB + FB + 1 + RB, 256, 0, stream>>>(
        edge_index, counts, proj_w, w_l, w_r, wt, rel_emb, w_e, erel,
        proj_b, b_l, b_r, fbias);

    // ---- CSR: two-level scan + packed scatter (edges constant across layers)
    scan_local_kernel<<<SB, 256, 0, stream>>>(counts, offsets, bsum);
    scan_bsum_kernel<<<1, 256, 0, stream>>>(bsum);
    scatter_kernel<<<(EE + 255) / 256, 256, 0, stream>>>(
        edge_index, edge_type, offsets, bsum, fill, dstorder);

    const int GB2 = (NN + 63) / 64;

    // ---- layer 0: proj folded into xl/xr — single GEMM reads node_features once
    gemm_bdirect_kernel<false, true, PK><<<GB2, 256, 0, stream>>>(
        node_features, entity, FF, FF,
        wt, fbias, xl,
        wt + (size_t)128 * PK, fbias + DD, xr, NN);
    node_kernel<<<(NN + 3) / 4, 256, 0, stream>>>(
        dstorder, offsets, bsum, xl, xr, erel,
        att, bias, xb, (float*)d_out, 0);

    // ---- layer 1: dual-output GEMM reads xb once
    gemm_bdirect_kernel<true, false, DD><<<GB2, 256, 0, stream>>>(
        xb, nullptr, DD, DD,
        wt + (size_t)2 * 128 * PK, b_l + DD, xl,
        wt + (size_t)2 * 128 * PK + 128 * 128, b_r + DD, xr, NN);
    node_kernel<<<(NN + 3) / 4, 256, 0, stream>>>(
        dstorder, offsets, bsum, xl, xr, erel + (size_t)RR * DD,
        att + DD, bias + DD, xb, (float*)d_out, 1);
}

// Round 3
// 327.065 us; speedup vs baseline: 1.0603x; 1.0101x over previous
//
#include <hip/hip_runtime.h>

#define NN 50000
#define FF 300
#define DD 128
#define HH 4
#define CC 32
#define EE 640000
#define RR 200
#define LL 2
#define SB ((NN + 255) / 256)     // scan blocks = 196
#define PK 320                    // proj K padded to multiple of 64
#define WCONV (2 * 128 * 128)     // layer-1 wl/wr transposed fp16
#define WTOT (2 * 128 * PK + WCONV)
#define HB ((EE + 255) / 256)     // hist blocks in prep (2500)
#define WB (WCONV / 256)          // wconv blocks (128)
#define FB PK                     // weight-fold blocks (320, 2 (lr,k) pairs each)
#define RB (LL * RR / 2)          // relproj blocks (200)

typedef unsigned short u16;
typedef unsigned int u32;
typedef _Float16 h2   __attribute__((ext_vector_type(2)));
typedef _Float16 half8 __attribute__((ext_vector_type(8)));  // MFMA A/B frag (4 VGPRs)
typedef __attribute__((ext_vector_type(4))) float floatx4;   // MFMA accumulator
typedef u32 u32x4 __attribute__((ext_vector_type(4)));       // 16B packed-half load

__device__ __forceinline__ u16 f2h(float f) {
    union { _Float16 h; u16 u; } v; v.h = (_Float16)f; return v.u;
}
__device__ __forceinline__ float h2f(u16 u) {
    union { u16 u; _Float16 h; } v; v.u = u; return (float)v.h;
}
__device__ __forceinline__ h2 u2h2(u32 p) {
    union { u32 u; h2 h; } v; v.u = p; return v.h;
}
__device__ __forceinline__ h2 hmax2(h2 a, h2 b) {
#if __has_builtin(__builtin_elementwise_max)
    return __builtin_elementwise_max(a, b);
#else
    h2 r; r.x = a.x > b.x ? a.x : b.x; r.y = a.y > b.y ? a.y : b.y; return r;
#endif
}
__device__ __forceinline__ float hdot2(h2 a, h2 b, float c) {
#if __has_builtin(__builtin_amdgcn_fdot2)
    return __builtin_amdgcn_fdot2(a, b, c, false);
#else
    return c + (float)a.x * (float)b.x + (float)a.y * (float)b.y;
#endif
}

// block-wide (256 threads) scan: returns exclusive prefix of v; *total = block sum
__device__ __forceinline__ int block_excl_scan(int v, int* lds4, int* total) {
    int lane = threadIdx.x & 63, wid = threadIdx.x >> 6;
    int x = v;
    #pragma unroll
    for (int off = 1; off < 64; off <<= 1) {
        int y = __shfl_up(x, off, 64);
        if (lane >= off) x += y;
    }
    if (lane == 63) lds4[wid] = x;
    __syncthreads();
    int add = 0;
    #pragma unroll
    for (int w = 0; w < 4; w++) add += (w < wid) ? lds4[w] : 0;
    *total = lds4[0] + lds4[1] + lds4[2] + lds4[3];
    return x + add - v;
}

// ---------------- fused prep:
// hist | layer1 weight transpose-convert | layer0 proj-fold GEMM | bias-fold | relproj
__global__ __launch_bounds__(256)
void prep_kernel(const int* __restrict__ ei, int* __restrict__ counts,
                 const float* __restrict__ proj_w, const float* __restrict__ w_l,
                 const float* __restrict__ w_r, u16* __restrict__ wt,
                 const float* __restrict__ rel_emb, const float* __restrict__ w_e,
                 u16* __restrict__ erel, const float* __restrict__ proj_b,
                 const float* __restrict__ b_l, const float* __restrict__ b_r,
                 float* __restrict__ fbias)
{
    __shared__ float rv[2][DD];
    int b = blockIdx.x, tid = threadIdx.x;
    if (b < HB) {
        // degree histogram
        int e = b * 256 + tid;
        if (e < EE) atomicAdd(&counts[ei[EE + e]], 1);
    } else if (b < HB + WB) {
        // layer-1 weights: fp32 [k][n] -> fp16 wt[n][k], segs [wl1][wr1]
        int i = (b - HB) * 256 + tid;        // < 32768
        int seg = i >> 14;                   // 0 = wl1, 1 = wr1
        int r = i & 16383;
        int n = r >> 7, k = r & 127;
        const float* src = (seg == 0 ? w_l : w_r) + (size_t)DD * DD;  // layer 1
        wt[2 * 128 * PK + i] = f2h(src[(size_t)k * DD + n]);
    } else if (b < HB + WB + FB) {
        // fused layer-0 weights: F[k][n] = sum_j Wp[k][j]*W{l,r}0[j][n],
        // stored transposed fp16: wt[lr*128*PK + n*PK + k]  (k>=FF -> 0 pad)
        int half = tid >> 7, d = tid & 127;
        int pp = (b - HB - WB) * 2 + half;   // 0..639 = (lr,k)
        int lr = pp / PK, k = pp - lr * PK;
        rv[half][d] = (k < FF) ? proj_w[(size_t)k * DD + d] : 0.f;
        __syncthreads();
        float acc = 0.f;
        if (k < FF) {
            const float* W = lr ? w_r : w_l;             // layer 0
            #pragma unroll 8
            for (int j = 0; j < DD; j++) acc += rv[half][j] * W[(size_t)j * DD + d];
        }
        wt[(size_t)lr * 128 * PK + (size_t)d * PK + k] = f2h(acc);
    } else if (b == HB + WB + FB) {
        // fused layer-0 bias: fb = b_{l,r}0 + proj_b @ W{l,r}0  (fp32)
        int half = tid >> 7, d = tid & 127;
        if (tid < DD) rv[0][tid] = proj_b[tid];
        __syncthreads();
        const float* W = half ? w_r : w_l;
        float acc = half ? b_r[d] : b_l[d];
        #pragma unroll 8
        for (int j = 0; j < DD; j++) acc += rv[0][j] * W[(size_t)j * DD + d];
        fbias[half * DD + d] = acc;
    } else {
        // erel[l*RR+r][d] = rel_emb[r,:] @ w_e[l][:,d]   (2 lr per block, fp16 out)
        int half = tid >> 7, d = tid & 127;
        int lr = (b - HB - WB - FB - 1) * 2 + half;
        int l = lr / RR, r = lr - l * RR;
        rv[half][d] = rel_emb[r * DD + d];
        __syncthreads();
        const float* W = w_e + (size_t)l * DD * DD;
        float acc = 0.f;
        #pragma unroll 8
        for (int k = 0; k < DD; k++) acc += rv[half][k] * W[k * DD + d];
        erel[(size_t)lr * DD + d] = f2h(acc);
    }
}

// ---------------- dual-output MFMA fp16 GEMM, tile 64 rows x 256 cols (both outputs).
// Entire 64xK A-tile staged into LDS in ONE phase (loads pipeline, no intervening
// barriers), then ONE __syncthreads(), then the full K loop of MFMAs with B fragments
// loaded directly from L2 (B is 40-160 KB, L2-resident). Two barriers per BLOCK total.
// As[64][K+8]: row stride mod 128B = 16 -> 64-lane ds_read_b128 hits the 8-cycle
// b128 floor with all banks busy (conflict-free).
template<bool AF16, bool GATHER, int K>
__global__ __launch_bounds__(256)
void gemm_stage1_kernel(const void* __restrict__ A_, const int* __restrict__ rowidx,
                        int lda, int Ka,
                        const u16* __restrict__ BT1, const float* __restrict__ bias1,
                        u16* __restrict__ C1,
                        const u16* __restrict__ BT2, const float* __restrict__ bias2,
                        u16* __restrict__ C2, int M)
{
    __shared__ u16 As[64][K + 8];
    int tid  = threadIdx.x;
    int m0   = blockIdx.x * 64;
    int wave = tid >> 6, lane = tid & 63;
    int quad = lane >> 4, l16 = lane & 15;
    // wave 0/1 -> C1 cols 0-63 / 64-127 ; wave 2/3 -> C2 cols 0-63 / 64-127
    const u16* BT = (wave < 2) ? BT1 : BT2;
    int wcol = (wave & 1) * 64;

    floatx4 acc[4][4];
    #pragma unroll
    for (int i = 0; i < 4; i++)
        #pragma unroll
        for (int j = 0; j < 4; j++) acc[i][j] = (floatx4){0.f, 0.f, 0.f, 0.f};

    // per-lane B row pointers (rows are MFMA cols); ldb == K for both weight blocks
    const u16* Brow[4];
    #pragma unroll
    for (int j = 0; j < 4; j++) Brow[j] = BT + (size_t)(wcol + j * 16 + l16) * K;

    int ar = tid >> 2, ac = (tid & 3) * 16;   // A: 64 rows x 4 threads, 16 halves/chunk
    int arow = m0 + ar;
    int rid = (arow < M) ? (GATHER ? rowidx[arow] : arow) : 0;

    // ---- stage ENTIRE A tile (K/64 chunks of 16 halves per thread), no barriers
    #pragma unroll
    for (int c = 0; c < K / 64; c++) {
        int kb = c * 64 + ac;
        u16 tmp[16];
        if (AF16) {
            const u16* Ap = (const u16*)A_ + (size_t)rid * lda + kb;
            *(half8*)&tmp[0] = *(const half8*)Ap;
            *(half8*)&tmp[8] = *(const half8*)(Ap + 8);
        } else {
            const float* Ap = (const float*)A_ + (size_t)rid * lda + kb;
            if (kb + 16 <= Ka) {
                #pragma unroll
                for (int qq = 0; qq < 4; qq++) {
                    float4 f = *(const float4*)(Ap + qq * 4);
                    tmp[qq*4+0] = f2h(f.x); tmp[qq*4+1] = f2h(f.y);
                    tmp[qq*4+2] = f2h(f.z); tmp[qq*4+3] = f2h(f.w);
                }
            } else {
                #pragma unroll
                for (int j = 0; j < 16; j++) tmp[j] = (kb + j < Ka) ? f2h(Ap[j]) : (u16)0;
            }
        }
        *(half8*)&As[ar][kb]     = *(half8*)&tmp[0];
        *(half8*)&As[ar][kb + 8] = *(half8*)&tmp[8];
    }
    __syncthreads();

    // ---- full K loop, barrier-free: B loads hoistable, ds_read->MFMA pipelined
    #pragma unroll
    for (int kk = 0; kk < K; kk += 32) {
        half8 af[4], bf[4];
        #pragma unroll
        for (int j = 0; j < 4; j++)
            bf[j] = *(const half8*)(Brow[j] + kk + quad * 8);
        #pragma unroll
        for (int i = 0; i < 4; i++)
            af[i] = *(const half8*)&As[i * 16 + l16][kk + quad * 8];
        #pragma unroll
        for (int i = 0; i < 4; i++)
            #pragma unroll
            for (int j = 0; j < 4; j++)
                acc[i][j] = __builtin_amdgcn_mfma_f32_16x16x32_f16(
                    af[i], bf[j], acc[i][j], 0, 0, 0);
    }

    // epilogue: C/D layout col=lane&15, row=quad*4+reg (m89; dtype-independent m121)
    u16* Cw = (wave < 2) ? C1 : C2;
    const float* bw = (wave < 2) ? bias1 : bias2;
    #pragma unroll
    for (int i = 0; i < 4; i++) {
        #pragma unroll
        for (int rr = 0; rr < 4; rr++) {
            int row = m0 + i * 16 + quad * 4 + rr;
            if (row < M) {
                #pragma unroll
                for (int j = 0; j < 4; j++) {
                    int col = wcol + j * 16 + l16;
                    Cw[(size_t)row * DD + col] = f2h(acc[i][j][rr] + bw[col]);
                }
            }
        }
    }
}

// ---------------- CSR scan (two-level, add folded into consumers) + scatter
__global__ __launch_bounds__(256)
void scan_local_kernel(const int* __restrict__ counts, int* __restrict__ offsets,
                       int* __restrict__ bsum)
{
    __shared__ int lds4[4];
    int i = blockIdx.x * 256 + threadIdx.x;
    int v = (i < NN) ? counts[i] : 0;
    int total;
    int ex = block_excl_scan(v, lds4, &total);
    if (i < NN) offsets[i] = ex;
    if (threadIdx.x == 0) bsum[blockIdx.x] = total;
}

__global__ __launch_bounds__(256)
void scan_bsum_kernel(int* __restrict__ bsum)
{
    __shared__ int lds4[4];
    int t = threadIdx.x;
    int v = (t < SB) ? bsum[t] : 0;
    int total;
    int ex = block_excl_scan(v, lds4, &total);
    if (t < SB) bsum[t] = ex;
}

// one random 4B write per edge (src 16b | type 16b packed; N<65536, R<256)
__global__ __launch_bounds__(256)
void scatter_kernel(const int* __restrict__ ei, const int* __restrict__ et,
                    const int* __restrict__ offsets, const int* __restrict__ bsum,
                    int* __restrict__ fill, u32* __restrict__ dstorder)
{
    int e = blockIdx.x * 256 + threadIdx.x;
    if (e >= EE) return;
    int d = ei[EE + e];
    int pos = offsets[d] + bsum[d >> 8] + atomicAdd(&fill[d], 1);
    dstorder[pos] = (u32)ei[e] | ((u32)et[e] << 16);
}

// ---------------- fused per-node: logits + softmax (no-shift) + aggregate + bias + act
// one wave per dst node; 4 edge-groups of 16 lanes; lane owns 8 channels (c0=(lane&15)*8)
// ALL fp16-packed math in the hot loop; gathers as single 16B vector loads.
__global__ __launch_bounds__(256)
void node_kernel(const u32* __restrict__ dstorder, const int* __restrict__ offsets,
                 const int* __restrict__ bsum,
                 const u16* __restrict__ xl, const u16* __restrict__ xr,
                 const u16* __restrict__ erel, const float* __restrict__ att,
                 const float* __restrict__ bias,
                 u16* __restrict__ xnext, float* __restrict__ outp, int is_last)
{
    int tid  = threadIdx.x;
    int node = blockIdx.x * 4 + (tid >> 6);
    int lane = tid & 63;
    if (node >= NN) return;
    int g  = lane >> 4;          // edge slot within quad
    int gl = lane & 15;          // channel set
    int c0 = gl * 8;
    int beg = offsets[node] + bsum[node >> 8];
    int end = (node == NN - 1) ? EE : offsets[node + 1] + bsum[(node + 1) >> 8];

    // per-node constants (packed fp16)
    h2 xrh[4], atth[4];
    {
        u32x4 xrv = *(const u32x4*)&xr[(size_t)node * DD + c0];
        #pragma unroll
        for (int q = 0; q < 4; q++) xrh[q] = u2h2(xrv[q]);
        #pragma unroll
        for (int q = 0; q < 4; q++) {
            float2 av = *(const float2*)&att[c0 + q * 2];
            atth[q] = (h2){(_Float16)av.x, (_Float16)av.y};
        }
    }
    const h2 c02 = (h2){(_Float16)0.2f, (_Float16)0.2f};

    float s = 0.f;
    h2 a2[4];
    #pragma unroll
    for (int q = 0; q < 4; q++) a2[q] = (h2){(_Float16)0.f, (_Float16)0.f};

    for (int base = beg; base < end; base += 4) {
        int es = base + g;
        bool valid = es < end;
        u32 st = valid ? dstorder[es] : 0;
        int src = st & 0xffff;
        int typ = st >> 16;
        // single 16B vector gathers (rows are 16B-aligned at c0)
        u32x4 xv = *(const u32x4*)&xl[(size_t)src * DD + c0];
        u32x4 ev = *(const u32x4*)&erel[(size_t)typ * DD + c0];
        h2 xh[4];
        float p = 0.f;
        #pragma unroll
        for (int q = 0; q < 4; q++) {
            xh[q] = u2h2(xv[q]);
            h2 m = (xh[q] + xrh[q]) + u2h2(ev[q]);   // v_pk_add_f16 x2
            m = hmax2(m, m * c02);                   // leaky: pk_mul + pk_max
            p = hdot2(m, atth[q], p);                // v_dot2_f32_f16 (fp32 acc)
        }
        // per-head logit: reduce over the 4 lanes of this head (gl span of 4)
        p += __shfl_xor(p, 1, 64);
        p += __shfl_xor(p, 2, 64);
        // softmax without max-shift: logits are O(1); clamp guards inf
        float w = valid ? __expf(fminf(p, 60.f)) : 0.f;
        s += w;
        h2 wh = (h2){(_Float16)w, (_Float16)w};
        #pragma unroll
        for (int q = 0; q < 4; q++) a2[q] += wh * xh[q];   // v_pk_fma_f16
    }

    // cross-group reduction (groups processed disjoint edges) — fp32 for safety
    float a[8];
    #pragma unroll
    for (int q = 0; q < 4; q++) { a[q*2] = (float)a2[q].x; a[q*2+1] = (float)a2[q].y; }
    #pragma unroll
    for (int j = 0; j < 8; j++) {
        a[j] += __shfl_xor(a[j], 16, 64);
        a[j] += __shfl_xor(a[j], 32, 64);
    }
    s += __shfl_xor(s, 16, 64);
    s += __shfl_xor(s, 32, 64);

    if (lane < 16) {
        float rh = 1.f / fmaxf(s, 1e-30f);
        float4 b0 = *(const float4*)&bias[c0];
        float4 b1 = *(const float4*)&bias[c0 + 4];
        float bv[8] = {b0.x, b0.y, b0.z, b0.w, b1.x, b1.y, b1.z, b1.w};
        float v[8];
        #pragma unroll
        for (int j = 0; j < 8; j++) v[j] = a[j] * rh + bv[j];
        if (is_last) {
            float4* op = (float4*)&outp[(size_t)node * DD + c0];
            op[0] = make_float4(v[0], v[1], v[2], v[3]);
            op[1] = make_float4(v[4], v[5], v[6], v[7]);
        } else {
            u16 pk[8];
            #pragma unroll
            for (int j = 0; j < 8; j++) {
                float w2 = v[j] > 0.f ? v[j] : __expf(v[j]) - 1.f;   // elu
                pk[j] = f2h(w2);
            }
            *(half8*)&xnext[(size_t)node * DD + c0] = *(half8*)pk;
        }
    }
}

extern "C" void kernel_launch(void* const* d_in, const int* in_sizes, int n_in,
                              void* d_out, int out_size, void* d_ws, size_t ws_size,
                              hipStream_t stream)
{
    const int*   entity        = (const int*)d_in[0];
    const int*   edge_index    = (const int*)d_in[1];
    const int*   edge_type     = (const int*)d_in[2];
    const float* node_features = (const float*)d_in[3];
    const float* rel_emb       = (const float*)d_in[4];
    const float* proj_w        = (const float*)d_in[5];
    const float* proj_b        = (const float*)d_in[6];
    const float* w_l           = (const float*)d_in[7];
    const float* b_l           = (const float*)d_in[8];
    const float* w_r           = (const float*)d_in[9];
    const float* b_r           = (const float*)d_in[10];
    const float* w_e           = (const float*)d_in[11];
    const float* att           = (const float*)d_in[12];
    const float* bias          = (const float*)d_in[13];

    // workspace (~42 MB), all fp16 tensors in u16 containers:
    u16*   xb      = (u16*)d_ws;                           // NN*DD (layer-0 output / layer-1 input)
    u16*   xl      = xb + (size_t)NN * DD;                 // NN*DD
    u16*   xr      = xl + (size_t)NN * DD;                 // NN*DD
    u16*   erel    = xr + (size_t)NN * DD;                 // LL*RR*DD
    u16*   wt      = erel + (size_t)LL * RR * DD;          // WTOT: [fusedL][fusedR][wl1][wr1]
    u32*   dstorder= (u32*)(wt + WTOT);                    // EE u32 (src|type, dst-order)
    int*   counts  = (int*)(dstorder + (size_t)EE);        // NN int
    int*   fill    = counts + NN;                          // NN int
    int*   offsets = fill + NN;                            // NN int (local scans)
    int*   bsum    = offsets + NN;                         // SB int
    float* fbias   = (float*)(bsum + SB);                  // 256 fp32 (folded layer-0 bias)

    // ---- prep: zero counts+fill, then fused hist | wconv | fold | biasfold | relproj
    hipMemsetAsync(counts, 0, (size_t)NN * 2 * sizeof(int), stream);
    prep_kernel<<<HB + WB + FB + 1 + RB, 256, 0, stream>>>(
        edge_index, counts, proj_w, w_l, w_r, wt, rel_emb, w_e, erel,
        proj_b, b_l, b_r, fbias);

    // ---- CSR: two-level scan + packed scatter (edges constant across layers)
    scan_local_kernel<<<SB, 256, 0, stream>>>(counts, offsets, bsum);
    scan_bsum_kernel<<<1, 256, 0, stream>>>(bsum);
    scatter_kernel<<<(EE + 255) / 256, 256, 0, stream>>>(
        edge_index, edge_type, offsets, bsum, fill, dstorder);

    const int GB2 = (NN + 63) / 64;

    // ---- layer 0: proj folded into xl/xr — single GEMM reads node_features once
    gemm_stage1_kernel<false, true, PK><<<GB2, 256, 0, stream>>>(
        node_features, entity, FF, FF,
        wt, fbias, xl,
        wt + (size_t)128 * PK, fbias + DD, xr, NN);
    node_kernel<<<(NN + 3) / 4, 256, 0, stream>>>(
        dstorder, offsets, bsum, xl, xr, erel,
        att, bias, xb, (float*)d_out, 0);

    // ---- layer 1: dual-output GEMM reads xb once
    gemm_stage1_kernel<true, false, DD><<<GB2, 256, 0, stream>>>(
        xb, nullptr, DD, DD,
        wt + (size_t)2 * 128 * PK, b_l + DD, xl,
        wt + (size_t)2 * 128 * PK + 128 * 128, b_r + DD, xr, NN);
    node_kernel<<<(NN + 3) / 4, 256, 0, stream>>>(
        dstorder, offsets, bsum, xl, xr, erel + (size_t)RR * DD,
        att + DD, bias + DD, xb, (float*)d_out, 1);
}

// Round 4
// 325.029 us; speedup vs baseline: 1.0669x; 1.0063x over previous
//
#include <hip/hip_runtime.h>

#define NN 50000
#define FF 300
#define DD 128
#define HH 4
#define CC 32
#define EE 640000
#define RR 200
#define LL 2
#define SB ((NN + 255) / 256)     // scan blocks = 196
#define PK 320                    // proj K padded to multiple of 64
#define WCONV (2 * 128 * 128)     // layer-1 wl/wr transposed fp16
#define WTOT (2 * 128 * PK + WCONV)
#define HB ((EE + 255) / 256)     // hist blocks in prep (2500)
#define WB (WCONV / 256)          // wconv blocks (128)
#define FB PK                     // weight-fold blocks (320, 2 (lr,k) pairs each)
#define RB (LL * RR / 2)          // relproj blocks (200)

typedef unsigned short u16;
typedef unsigned int u32;
typedef _Float16 h2   __attribute__((ext_vector_type(2)));
typedef _Float16 half8 __attribute__((ext_vector_type(8)));  // MFMA A/B frag (4 VGPRs)
typedef __attribute__((ext_vector_type(4))) float floatx4;   // MFMA accumulator
typedef u32 u32x4 __attribute__((ext_vector_type(4)));       // 16B packed-half load

__device__ __forceinline__ u16 f2h(float f) {
    union { _Float16 h; u16 u; } v; v.h = (_Float16)f; return v.u;
}
__device__ __forceinline__ float h2f(u16 u) {
    union { u16 u; _Float16 h; } v; v.u = u; return (float)v.h;
}
__device__ __forceinline__ h2 u2h2(u32 p) {
    union { u32 u; h2 h; } v; v.u = p; return v.h;
}
__device__ __forceinline__ h2 hmax2(h2 a, h2 b) {
#if __has_builtin(__builtin_elementwise_max)
    return __builtin_elementwise_max(a, b);
#else
    h2 r; r.x = a.x > b.x ? a.x : b.x; r.y = a.y > b.y ? a.y : b.y; return r;
#endif
}
__device__ __forceinline__ float hdot2(h2 a, h2 b, float c) {
#if __has_builtin(__builtin_amdgcn_fdot2)
    return __builtin_amdgcn_fdot2(a, b, c, false);
#else
    return c + (float)a.x * (float)b.x + (float)a.y * (float)b.y;
#endif
}

// block-wide (256 threads) scan: returns exclusive prefix of v; *total = block sum
__device__ __forceinline__ int block_excl_scan(int v, int* lds4, int* total) {
    int lane = threadIdx.x & 63, wid = threadIdx.x >> 6;
    int x = v;
    #pragma unroll
    for (int off = 1; off < 64; off <<= 1) {
        int y = __shfl_up(x, off, 64);
        if (lane >= off) x += y;
    }
    if (lane == 63) lds4[wid] = x;
    __syncthreads();
    int add = 0;
    #pragma unroll
    for (int w = 0; w < 4; w++) add += (w < wid) ? lds4[w] : 0;
    *total = lds4[0] + lds4[1] + lds4[2] + lds4[3];
    return x + add - v;
}

// ---------------- fused prep:
// hist | layer1 weight transpose-convert | layer0 proj-fold GEMM | bias-fold | relproj
__global__ __launch_bounds__(256)
void prep_kernel(const int* __restrict__ ei, int* __restrict__ counts,
                 const float* __restrict__ proj_w, const float* __restrict__ w_l,
                 const float* __restrict__ w_r, u16* __restrict__ wt,
                 const float* __restrict__ rel_emb, const float* __restrict__ w_e,
                 u16* __restrict__ erel, const float* __restrict__ proj_b,
                 const float* __restrict__ b_l, const float* __restrict__ b_r,
                 float* __restrict__ fbias)
{
    __shared__ float rv[2][DD];
    int b = blockIdx.x, tid = threadIdx.x;
    if (b < HB) {
        // degree histogram
        int e = b * 256 + tid;
        if (e < EE) atomicAdd(&counts[ei[EE + e]], 1);
    } else if (b < HB + WB) {
        // layer-1 weights: fp32 [k][n] -> fp16 wt[n][k], segs [wl1][wr1]
        int i = (b - HB) * 256 + tid;        // < 32768
        int seg = i >> 14;                   // 0 = wl1, 1 = wr1
        int r = i & 16383;
        int n = r >> 7, k = r & 127;
        const float* src = (seg == 0 ? w_l : w_r) + (size_t)DD * DD;  // layer 1
        wt[2 * 128 * PK + i] = f2h(src[(size_t)k * DD + n]);
    } else if (b < HB + WB + FB) {
        // fused layer-0 weights: F[k][n] = sum_j Wp[k][j]*W{l,r}0[j][n],
        // stored transposed fp16: wt[lr*128*PK + n*PK + k]  (k>=FF -> 0 pad)
        int half = tid >> 7, d = tid & 127;
        int pp = (b - HB - WB) * 2 + half;   // 0..639 = (lr,k)
        int lr = pp / PK, k = pp - lr * PK;
        rv[half][d] = (k < FF) ? proj_w[(size_t)k * DD + d] : 0.f;
        __syncthreads();
        float acc = 0.f;
        if (k < FF) {
            const float* W = lr ? w_r : w_l;             // layer 0
            #pragma unroll 8
            for (int j = 0; j < DD; j++) acc += rv[half][j] * W[(size_t)j * DD + d];
        }
        wt[(size_t)lr * 128 * PK + (size_t)d * PK + k] = f2h(acc);
    } else if (b == HB + WB + FB) {
        // fused layer-0 bias: fb = b_{l,r}0 + proj_b @ W{l,r}0  (fp32)
        int half = tid >> 7, d = tid & 127;
        if (tid < DD) rv[0][tid] = proj_b[tid];
        __syncthreads();
        const float* W = half ? w_r : w_l;
        float acc = half ? b_r[d] : b_l[d];
        #pragma unroll 8
        for (int j = 0; j < DD; j++) acc += rv[0][j] * W[(size_t)j * DD + d];
        fbias[half * DD + d] = acc;
    } else {
        // erel[l*RR+r][d] = rel_emb[r,:] @ w_e[l][:,d]   (2 lr per block, fp16 out)
        int half = tid >> 7, d = tid & 127;
        int lr = (b - HB - WB - FB - 1) * 2 + half;
        int l = lr / RR, r = lr - l * RR;
        rv[half][d] = rel_emb[r * DD + d];
        __syncthreads();
        const float* W = w_e + (size_t)l * DD * DD;
        float acc = 0.f;
        #pragma unroll 8
        for (int k = 0; k < DD; k++) acc += rv[half][k] * W[k * DD + d];
        erel[(size_t)lr * DD + d] = f2h(acc);
    }
}

// ---------------- dual-output MFMA fp16 GEMM, tile 64 rows x 256 cols, 8 WAVES.
// Each wave owns 32 output cols (waves 0-3 -> C1, 4-7 -> C2): acc = 4x2 x floatx4.
// 24 waves/CU at 3 blocks/CU (vs 12 before) to hide A (HBM/L3) + B (L2) latency.
// A-tile staged once (coalesced 256B row segments), ONE barrier; B fragments read
// directly from L2 with a rolling 1-step register prefetch started BEFORE the barrier.
template<bool AF16, bool GATHER, int K>
__global__ __launch_bounds__(512)
void gemm8_kernel(const void* __restrict__ A_, const int* __restrict__ rowidx,
                  int lda, int Ka,
                  const u16* __restrict__ BT1, const float* __restrict__ bias1,
                  u16* __restrict__ C1,
                  const u16* __restrict__ BT2, const float* __restrict__ bias2,
                  u16* __restrict__ C2, int M)
{
    __shared__ u16 As[64][K + 8];
    int tid  = threadIdx.x;
    int m0   = blockIdx.x * 64;
    int wave = tid >> 6, lane = tid & 63;
    int quad = lane >> 4, l16 = lane & 15;
    const u16* BT = (wave < 4) ? BT1 : BT2;
    int wcol = (wave & 3) * 32;

    floatx4 acc[4][2];
    #pragma unroll
    for (int i = 0; i < 4; i++)
        #pragma unroll
        for (int j = 0; j < 2; j++) acc[i][j] = (floatx4){0.f, 0.f, 0.f, 0.f};

    // per-lane B row pointers (rows are MFMA cols); ldb == K for both weight blocks
    const u16* Brow[2];
    #pragma unroll
    for (int j = 0; j < 2; j++) Brow[j] = BT + (size_t)(wcol + j * 16 + l16) * K;

    // B prefetch for k-step 0 issued BEFORE staging/barrier (independent of LDS)
    half8 bfc[2];
    #pragma unroll
    for (int j = 0; j < 2; j++) bfc[j] = *(const half8*)(Brow[j] + quad * 8);

    // ---- stage A tile: 64 rows x 8 threads/row, chunk = 8 halves, fully coalesced
    int ar = tid >> 3, at = tid & 7;
    int arow = m0 + ar;
    int rid = (arow < M) ? (GATHER ? rowidx[arow] : arow) : 0;
    #pragma unroll
    for (int c = 0; c < K / 64; c++) {
        int kb = c * 64 + at * 8;
        u16 tmp[8];
        if (AF16) {
            const u16* Ap = (const u16*)A_ + (size_t)rid * lda + kb;
            *(half8*)tmp = *(const half8*)Ap;
        } else {
            const float* Ap = (const float*)A_ + (size_t)rid * lda + kb;
            if (kb + 8 <= Ka) {
                float4 f0 = *(const float4*)Ap;
                float4 f1 = *(const float4*)(Ap + 4);
                tmp[0] = f2h(f0.x); tmp[1] = f2h(f0.y); tmp[2] = f2h(f0.z); tmp[3] = f2h(f0.w);
                tmp[4] = f2h(f1.x); tmp[5] = f2h(f1.y); tmp[6] = f2h(f1.z); tmp[7] = f2h(f1.w);
            } else {
                #pragma unroll
                for (int jj = 0; jj < 8; jj++) tmp[jj] = (kb + jj < Ka) ? f2h(Ap[jj]) : (u16)0;
            }
        }
        *(half8*)&As[ar][kb] = *(half8*)tmp;
    }
    __syncthreads();

    // ---- K loop: rolling B prefetch, barrier-free, ds_read -> MFMA pipelined
    #pragma unroll
    for (int kk = 0; kk < K; kk += 32) {
        half8 bfn[2];
        if (kk + 32 < K) {
            #pragma unroll
            for (int j = 0; j < 2; j++)
                bfn[j] = *(const half8*)(Brow[j] + kk + 32 + quad * 8);
        }
        half8 af[4];
        #pragma unroll
        for (int i = 0; i < 4; i++)
            af[i] = *(const half8*)&As[i * 16 + l16][kk + quad * 8];
        #pragma unroll
        for (int i = 0; i < 4; i++)
            #pragma unroll
            for (int j = 0; j < 2; j++)
                acc[i][j] = __builtin_amdgcn_mfma_f32_16x16x32_f16(
                    af[i], bfc[j], acc[i][j], 0, 0, 0);
        bfc[0] = bfn[0]; bfc[1] = bfn[1];
    }

    // epilogue: C/D layout col=lane&15, row=quad*4+reg (m89; dtype-independent m121)
    u16* Cw = (wave < 4) ? C1 : C2;
    const float* bw = (wave < 4) ? bias1 : bias2;
    #pragma unroll
    for (int i = 0; i < 4; i++) {
        #pragma unroll
        for (int rr = 0; rr < 4; rr++) {
            int row = m0 + i * 16 + quad * 4 + rr;
            if (row < M) {
                #pragma unroll
                for (int j = 0; j < 2; j++) {
                    int col = wcol + j * 16 + l16;
                    Cw[(size_t)row * DD + col] = f2h(acc[i][j][rr] + bw[col]);
                }
            }
        }
    }
}

// ---------------- CSR scan (two-level, add folded into consumers) + scatter
__global__ __launch_bounds__(256)
void scan_local_kernel(const int* __restrict__ counts, int* __restrict__ offsets,
                       int* __restrict__ bsum)
{
    __shared__ int lds4[4];
    int i = blockIdx.x * 256 + threadIdx.x;
    int v = (i < NN) ? counts[i] : 0;
    int total;
    int ex = block_excl_scan(v, lds4, &total);
    if (i < NN) offsets[i] = ex;
    if (threadIdx.x == 0) bsum[blockIdx.x] = total;
}

__global__ __launch_bounds__(256)
void scan_bsum_kernel(int* __restrict__ bsum)
{
    __shared__ int lds4[4];
    int t = threadIdx.x;
    int v = (t < SB) ? bsum[t] : 0;
    int total;
    int ex = block_excl_scan(v, lds4, &total);
    if (t < SB) bsum[t] = ex;
}

// one random 4B write per edge (src 16b | type 16b packed; N<65536, R<256)
__global__ __launch_bounds__(256)
void scatter_kernel(const int* __restrict__ ei, const int* __restrict__ et,
                    const int* __restrict__ offsets, const int* __restrict__ bsum,
                    int* __restrict__ fill, u32* __restrict__ dstorder)
{
    int e = blockIdx.x * 256 + threadIdx.x;
    if (e >= EE) return;
    int d = ei[EE + e];
    int pos = offsets[d] + bsum[d >> 8] + atomicAdd(&fill[d], 1);
    dstorder[pos] = (u32)ei[e] | ((u32)et[e] << 16);
}

// ---------------- fused per-node: logits + softmax (no-shift) + aggregate + bias + act
// one wave per dst node; 4 edge-groups of 16 lanes; lane owns 8 channels (c0=(lane&15)*8)
// ALL fp16-packed math; gathers via 32-bit element offsets (saddr form, less VALU).
__global__ __launch_bounds__(256)
void node_kernel(const u32* __restrict__ dstorder, const int* __restrict__ offsets,
                 const int* __restrict__ bsum,
                 const u16* __restrict__ xl, const u16* __restrict__ xr,
                 const u16* __restrict__ erel, const float* __restrict__ att,
                 const float* __restrict__ bias,
                 u16* __restrict__ xnext, float* __restrict__ outp, int is_last)
{
    int tid  = threadIdx.x;
    int node = blockIdx.x * 4 + (tid >> 6);
    int lane = tid & 63;
    if (node >= NN) return;
    int g  = lane >> 4;          // edge slot within quad
    int gl = lane & 15;          // channel set
    int c0 = gl * 8;
    int beg = offsets[node] + bsum[node >> 8];
    int end = (node == NN - 1) ? EE : offsets[node + 1] + bsum[(node + 1) >> 8];

    // per-node constants (packed fp16)
    h2 xrh[4], atth[4];
    {
        u32x4 xrv = *(const u32x4*)(xr + ((u32)node * DD + c0));
        #pragma unroll
        for (int q = 0; q < 4; q++) xrh[q] = u2h2(xrv[q]);
        #pragma unroll
        for (int q = 0; q < 4; q++) {
            float2 av = *(const float2*)&att[c0 + q * 2];
            atth[q] = (h2){(_Float16)av.x, (_Float16)av.y};
        }
    }
    const h2 c02 = (h2){(_Float16)0.2f, (_Float16)0.2f};

    float s = 0.f;
    h2 a2[4];
    #pragma unroll
    for (int q = 0; q < 4; q++) a2[q] = (h2){(_Float16)0.f, (_Float16)0.f};

    for (int base = beg; base < end; base += 4) {
        int es = base + g;
        bool valid = es < end;
        u32 st = valid ? dstorder[es] : 0;
        // 32-bit element offsets: src*128+c0 < 6.4M, typ*128+c0 < 51200
        u32 xoff = (st & 0xffffu) * DD + (u32)c0;
        u32 eoff = (st >> 16) * DD + (u32)c0;
        u32x4 xv = *(const u32x4*)(xl + xoff);
        u32x4 ev = *(const u32x4*)(erel + eoff);
        h2 xh[4];
        float p = 0.f;
        #pragma unroll
        for (int q = 0; q < 4; q++) {
            xh[q] = u2h2(xv[q]);
            h2 m = (xh[q] + xrh[q]) + u2h2(ev[q]);   // v_pk_add_f16 x2
            m = hmax2(m, m * c02);                   // leaky: pk_mul + pk_max
            p = hdot2(m, atth[q], p);                // v_dot2_f32_f16 (fp32 acc)
        }
        // per-head logit: reduce over the 4 lanes of this head (gl span of 4)
        p += __shfl_xor(p, 1, 64);
        p += __shfl_xor(p, 2, 64);
        // softmax without max-shift: logits are O(1); clamp guards inf
        float w = valid ? __expf(fminf(p, 60.f)) : 0.f;
        s += w;
        h2 wh = (h2){(_Float16)w, (_Float16)w};
        #pragma unroll
        for (int q = 0; q < 4; q++) a2[q] += wh * xh[q];   // v_pk_fma_f16
    }

    // cross-group reduction (groups processed disjoint edges) — fp32 for safety
    float a[8];
    #pragma unroll
    for (int q = 0; q < 4; q++) { a[q*2] = (float)a2[q].x; a[q*2+1] = (float)a2[q].y; }
    #pragma unroll
    for (int j = 0; j < 8; j++) {
        a[j] += __shfl_xor(a[j], 16, 64);
        a[j] += __shfl_xor(a[j], 32, 64);
    }
    s += __shfl_xor(s, 16, 64);
    s += __shfl_xor(s, 32, 64);

    if (lane < 16) {
        float rh = 1.f / fmaxf(s, 1e-30f);
        float4 b0 = *(const float4*)&bias[c0];
        float4 b1 = *(const float4*)&bias[c0 + 4];
        float bv[8] = {b0.x, b0.y, b0.z, b0.w, b1.x, b1.y, b1.z, b1.w};
        float v[8];
        #pragma unroll
        for (int j = 0; j < 8; j++) v[j] = a[j] * rh + bv[j];
        if (is_last) {
            float4* op = (float4*)(outp + ((u32)node * DD + c0));
            op[0] = make_float4(v[0], v[1], v[2], v[3]);
            op[1] = make_float4(v[4], v[5], v[6], v[7]);
        } else {
            u16 pk[8];
            #pragma unroll
            for (int j = 0; j < 8; j++) {
                float w2 = v[j] > 0.f ? v[j] : __expf(v[j]) - 1.f;   // elu
                pk[j] = f2h(w2);
            }
            *(half8*)(xnext + ((u32)node * DD + c0)) = *(half8*)pk;
        }
    }
}

extern "C" void kernel_launch(void* const* d_in, const int* in_sizes, int n_in,
                              void* d_out, int out_size, void* d_ws, size_t ws_size,
                              hipStream_t stream)
{
    const int*   entity        = (const int*)d_in[0];
    const int*   edge_index    = (const int*)d_in[1];
    const int*   edge_type     = (const int*)d_in[2];
    const float* node_features = (const float*)d_in[3];
    const float* rel_emb       = (const float*)d_in[4];
    const float* proj_w        = (const float*)d_in[5];
    const float* proj_b        = (const float*)d_in[6];
    const float* w_l           = (const float*)d_in[7];
    const float* b_l           = (const float*)d_in[8];
    const float* w_r           = (const float*)d_in[9];
    const float* b_r           = (const float*)d_in[10];
    const float* w_e           = (const float*)d_in[11];
    const float* att           = (const float*)d_in[12];
    const float* bias          = (const float*)d_in[13];

    // workspace (~42 MB), all fp16 tensors in u16 containers:
    u16*   xb      = (u16*)d_ws;                           // NN*DD (layer-0 output / layer-1 input)
    u16*   xl      = xb + (size_t)NN * DD;                 // NN*DD
    u16*   xr      = xl + (size_t)NN * DD;                 // NN*DD
    u16*   erel    = xr + (size_t)NN * DD;                 // LL*RR*DD
    u16*   wt      = erel + (size_t)LL * RR * DD;          // WTOT: [fusedL][fusedR][wl1][wr1]
    u32*   dstorder= (u32*)(wt + WTOT);                    // EE u32 (src|type, dst-order)
    int*   counts  = (int*)(dstorder + (size_t)EE);        // NN int
    int*   fill    = counts + NN;                          // NN int
    int*   offsets = fill + NN;                            // NN int (local scans)
    int*   bsum    = offsets + NN;                         // SB int
    float* fbias   = (float*)(bsum + SB);                  // 256 fp32 (folded layer-0 bias)

    // ---- prep: zero counts+fill, then fused hist | wconv | fold | biasfold | relproj
    hipMemsetAsync(counts, 0, (size_t)NN * 2 * sizeof(int), stream);
    prep_kernel<<<HB + WB + FB + 1 + RB, 256, 0, stream>>>(
        edge_index, counts, proj_w, w_l, w_r, wt, rel_emb, w_e, erel,
        proj_b, b_l, b_r, fbias);

    // ---- CSR: two-level scan + packed scatter (edges constant across layers)
    scan_local_kernel<<<SB, 256, 0, stream>>>(counts, offsets, bsum);
    scan_bsum_kernel<<<1, 256, 0, stream>>>(bsum);
    scatter_kernel<<<(EE + 255) / 256, 256, 0, stream>>>(
        edge_index, edge_type, offsets, bsum, fill, dstorder);

    const int GB2 = (NN + 63) / 64;

    // ---- layer 0: proj folded into xl/xr — single GEMM reads node_features once
    gemm8_kernel<false, true, PK><<<GB2, 512, 0, stream>>>(
        node_features, entity, FF, FF,
        wt, fbias, xl,
        wt + (size_t)128 * PK, fbias + DD, xr, NN);
    node_kernel<<<(NN + 3) / 4, 256, 0, stream>>>(
        dstorder, offsets, bsum, xl, xr, erel,
        att, bias, xb, (float*)d_out, 0);

    // ---- layer 1: dual-output GEMM reads xb once
    gemm8_kernel<true, false, DD><<<GB2, 512, 0, stream>>>(
        xb, nullptr, DD, DD,
        wt + (size_t)2 * 128 * PK, b_l + DD, xl,
        wt + (size_t)2 * 128 * PK + 128 * 128, b_r + DD, xr, NN);
    node_kernel<<<(NN + 3) / 4, 256, 0, stream>>>(
        dstorder, offsets, bsum, xl, xr, erel + (size_t)RR * DD,
        att + DD, bias + DD, xb, (float*)d_out, 1);
}

// Round 5
// 322.202 us; speedup vs baseline: 1.0763x; 1.0088x over previous
//
#include <hip/hip_runtime.h>

#define NN 50000
#define FF 300
#define DD 128
#define HH 4
#define CC 32
#define EE 640000
#define RR 200
#define LL 2
#define SB ((NN + 255) / 256)     // scan blocks = 196
#define PK 320                    // proj K padded to multiple of 64
#define WCONV (2 * 128 * 128)     // layer-1 wl/wr transposed fp16
#define WTOT (2 * 128 * PK + WCONV)
#define HB ((EE + 255) / 256)     // hist blocks in prep (2500)
#define WB (WCONV / 256)          // wconv blocks (128)
#define FB PK                     // weight-fold blocks (320, 2 (lr,k) pairs each)
#define RB (LL * RR / 2)          // relproj blocks (200)

typedef unsigned short u16;
typedef unsigned int u32;
typedef _Float16 h2   __attribute__((ext_vector_type(2)));
typedef _Float16 half8 __attribute__((ext_vector_type(8)));  // MFMA A/B frag (4 VGPRs)
typedef __attribute__((ext_vector_type(4))) float floatx4;   // MFMA accumulator
typedef u32 u32x4 __attribute__((ext_vector_type(4)));       // 16B packed-half load

__device__ __forceinline__ u16 f2h(float f) {
    union { _Float16 h; u16 u; } v; v.h = (_Float16)f; return v.u;
}
__device__ __forceinline__ float h2f(u16 u) {
    union { u16 u; _Float16 h; } v; v.u = u; return (float)v.h;
}
__device__ __forceinline__ h2 u2h2(u32 p) {
    union { u32 u; h2 h; } v; v.u = p; return v.h;
}
__device__ __forceinline__ h2 hmax2(h2 a, h2 b) {
#if __has_builtin(__builtin_elementwise_max)
    return __builtin_elementwise_max(a, b);
#else
    h2 r; r.x = a.x > b.x ? a.x : b.x; r.y = a.y > b.y ? a.y : b.y; return r;
#endif
}
__device__ __forceinline__ float hdot2(h2 a, h2 b, float c) {
#if __has_builtin(__builtin_amdgcn_fdot2)
    return __builtin_amdgcn_fdot2(a, b, c, false);
#else
    return c + (float)a.x * (float)b.x + (float)a.y * (float)b.y;
#endif
}

// block-wide (256 threads) scan: returns exclusive prefix of v; *total = block sum
__device__ __forceinline__ int block_excl_scan(int v, int* lds4, int* total) {
    int lane = threadIdx.x & 63, wid = threadIdx.x >> 6;
    int x = v;
    #pragma unroll
    for (int off = 1; off < 64; off <<= 1) {
        int y = __shfl_up(x, off, 64);
        if (lane >= off) x += y;
    }
    if (lane == 63) lds4[wid] = x;
    __syncthreads();
    int add = 0;
    #pragma unroll
    for (int w = 0; w < 4; w++) add += (w < wid) ? lds4[w] : 0;
    *total = lds4[0] + lds4[1] + lds4[2] + lds4[3];
    return x + add - v;
}

// ---------------- fused prep:
// hist | layer1 weight transpose-convert | layer0 proj-fold GEMM | bias-fold | relproj
__global__ __launch_bounds__(256)
void prep_kernel(const int* __restrict__ ei, int* __restrict__ counts,
                 const float* __restrict__ proj_w, const float* __restrict__ w_l,
                 const float* __restrict__ w_r, u16* __restrict__ wt,
                 const float* __restrict__ rel_emb, const float* __restrict__ w_e,
                 u16* __restrict__ erel, const float* __restrict__ proj_b,
                 const float* __restrict__ b_l, const float* __restrict__ b_r,
                 float* __restrict__ fbias)
{
    __shared__ float rv[2][DD];
    int b = blockIdx.x, tid = threadIdx.x;
    if (b < HB) {
        // degree histogram
        int e = b * 256 + tid;
        if (e < EE) atomicAdd(&counts[ei[EE + e]], 1);
    } else if (b < HB + WB) {
        // layer-1 weights: fp32 [k][n] -> fp16 wt[n][k], segs [wl1][wr1]
        int i = (b - HB) * 256 + tid;        // < 32768
        int seg = i >> 14;                   // 0 = wl1, 1 = wr1
        int r = i & 16383;
        int n = r >> 7, k = r & 127;
        const float* src = (seg == 0 ? w_l : w_r) + (size_t)DD * DD;  // layer 1
        wt[2 * 128 * PK + i] = f2h(src[(size_t)k * DD + n]);
    } else if (b < HB + WB + FB) {
        // fused layer-0 weights: F[k][n] = sum_j Wp[k][j]*W{l,r}0[j][n],
        // stored transposed fp16: wt[lr*128*PK + n*PK + k]  (k>=FF -> 0 pad)
        int half = tid >> 7, d = tid & 127;
        int pp = (b - HB - WB) * 2 + half;   // 0..639 = (lr,k)
        int lr = pp / PK, k = pp - lr * PK;
        rv[half][d] = (k < FF) ? proj_w[(size_t)k * DD + d] : 0.f;
        __syncthreads();
        float acc = 0.f;
        if (k < FF) {
            const float* W = lr ? w_r : w_l;             // layer 0
            #pragma unroll 8
            for (int j = 0; j < DD; j++) acc += rv[half][j] * W[(size_t)j * DD + d];
        }
        wt[(size_t)lr * 128 * PK + (size_t)d * PK + k] = f2h(acc);
    } else if (b == HB + WB + FB) {
        // fused layer-0 bias: fb = b_{l,r}0 + proj_b @ W{l,r}0  (fp32)
        int half = tid >> 7, d = tid & 127;
        if (tid < DD) rv[0][tid] = proj_b[tid];
        __syncthreads();
        const float* W = half ? w_r : w_l;
        float acc = half ? b_r[d] : b_l[d];
        #pragma unroll 8
        for (int j = 0; j < DD; j++) acc += rv[0][j] * W[(size_t)j * DD + d];
        fbias[half * DD + d] = acc;
    } else {
        // erel[l*RR+r][d] = rel_emb[r,:] @ w_e[l][:,d]   (2 lr per block, fp16 out)
        int half = tid >> 7, d = tid & 127;
        int lr = (b - HB - WB - FB - 1) * 2 + half;
        int l = lr / RR, r = lr - l * RR;
        rv[half][d] = rel_emb[r * DD + d];
        __syncthreads();
        const float* W = w_e + (size_t)l * DD * DD;
        float acc = 0.f;
        #pragma unroll 8
        for (int k = 0; k < DD; k++) acc += rv[half][k] * W[k * DD + d];
        erel[(size_t)lr * DD + d] = f2h(acc);
    }
}

// ---------------- dual-output MFMA fp16 GEMM, tile 64 rows x 256 cols, 8 waves.
// Wave owns 32 cols (waves 0-3 -> C1, 4-7 -> C2): acc = 4x2 floatx4 (32 VGPR).
// B held in a 4-DEEP circular register queue (32 VGPR): all 4 stages issued BEFORE
// the A-stage+barrier (overlap A's HBM latency); each consumed slot refilled 4
// k-steps ahead. For K=128 the queue covers ALL of B -> K-loop has zero global loads.
// __launch_bounds__(512,3): LDS caps 3 blocks/CU anyway; give allocator ~170 VGPRs
// so the queue stays in registers (round-4's 44-VGPR allocation serialized loads).
template<bool AF16, bool GATHER, int K>
__global__ __launch_bounds__(512, 3)
void gemm8_kernel(const void* __restrict__ A_, const int* __restrict__ rowidx,
                  int lda, int Ka,
                  const u16* __restrict__ BT1, const float* __restrict__ bias1,
                  u16* __restrict__ C1,
                  const u16* __restrict__ BT2, const float* __restrict__ bias2,
                  u16* __restrict__ C2, int M)
{
    constexpr int NSTEP = K / 32;
    __shared__ u16 As[64][K + 8];
    int tid  = threadIdx.x;
    int m0   = blockIdx.x * 64;
    int wave = tid >> 6, lane = tid & 63;
    int quad = lane >> 4, l16 = lane & 15;
    const u16* BT = (wave < 4) ? BT1 : BT2;
    int wcol = (wave & 3) * 32;

    floatx4 acc[4][2];
    #pragma unroll
    for (int i = 0; i < 4; i++)
        #pragma unroll
        for (int j = 0; j < 2; j++) acc[i][j] = (floatx4){0.f, 0.f, 0.f, 0.f};

    // per-lane B row pointers (rows are MFMA cols); ldb == K for both weight blocks
    const u16* Brow[2];
    #pragma unroll
    for (int j = 0; j < 2; j++) Brow[j] = BT + (size_t)(wcol + j * 16 + l16) * K;

    // ---- B prologue: fill 4-deep queue (oldest first), before any A traffic
    half8 bq[4][2];
    #pragma unroll
    for (int d = 0; d < 4; d++) {
        if (d < NSTEP) {
            #pragma unroll
            for (int j = 0; j < 2; j++)
                bq[d][j] = *(const half8*)(Brow[j] + d * 32 + quad * 8);
        }
    }

    // ---- stage A tile: 64 rows x 8 threads/row, chunk = 8 halves, fully coalesced
    int ar = tid >> 3, at = tid & 7;
    int arow = m0 + ar;
    int rid = (arow < M) ? (GATHER ? rowidx[arow] : arow) : 0;
    #pragma unroll
    for (int c = 0; c < K / 64; c++) {
        int kb = c * 64 + at * 8;
        u16 tmp[8];
        if (AF16) {
            const u16* Ap = (const u16*)A_ + (size_t)rid * lda + kb;
            *(half8*)tmp = *(const half8*)Ap;
        } else {
            const float* Ap = (const float*)A_ + (size_t)rid * lda + kb;
            if (kb + 8 <= Ka) {
                float4 f0 = *(const float4*)Ap;
                float4 f1 = *(const float4*)(Ap + 4);
                tmp[0] = f2h(f0.x); tmp[1] = f2h(f0.y); tmp[2] = f2h(f0.z); tmp[3] = f2h(f0.w);
                tmp[4] = f2h(f1.x); tmp[5] = f2h(f1.y); tmp[6] = f2h(f1.z); tmp[7] = f2h(f1.w);
            } else {
                #pragma unroll
                for (int jj = 0; jj < 8; jj++) tmp[jj] = (kb + jj < Ka) ? f2h(Ap[jj]) : (u16)0;
            }
        }
        *(half8*)&As[ar][kb] = *(half8*)tmp;
    }
    __syncthreads();

    // ---- K loop (fully unrolled, static queue indices): consume slot s&3,
    // refill it with step s+4's fragments, MFMA from registers.
    #pragma unroll
    for (int s = 0; s < NSTEP; s++) {
        half8 af[4];
        #pragma unroll
        for (int i = 0; i < 4; i++)
            af[i] = *(const half8*)&As[i * 16 + l16][s * 32 + quad * 8];
        half8 b0 = bq[s & 3][0], b1 = bq[s & 3][1];
        if (s + 4 < NSTEP) {
            #pragma unroll
            for (int j = 0; j < 2; j++)
                bq[s & 3][j] = *(const half8*)(Brow[j] + (s + 4) * 32 + quad * 8);
        }
        #pragma unroll
        for (int i = 0; i < 4; i++) {
            acc[i][0] = __builtin_amdgcn_mfma_f32_16x16x32_f16(af[i], b0, acc[i][0], 0, 0, 0);
            acc[i][1] = __builtin_amdgcn_mfma_f32_16x16x32_f16(af[i], b1, acc[i][1], 0, 0, 0);
        }
    }

    // epilogue: C/D layout col=lane&15, row=quad*4+reg (m89; dtype-independent m121)
    u16* Cw = (wave < 4) ? C1 : C2;
    const float* bw = (wave < 4) ? bias1 : bias2;
    #pragma unroll
    for (int i = 0; i < 4; i++) {
        #pragma unroll
        for (int rr = 0; rr < 4; rr++) {
            int row = m0 + i * 16 + quad * 4 + rr;
            if (row < M) {
                #pragma unroll
                for (int j = 0; j < 2; j++) {
                    int col = wcol + j * 16 + l16;
                    Cw[(size_t)row * DD + col] = f2h(acc[i][j][rr] + bw[col]);
                }
            }
        }
    }
}

// ---------------- CSR scan (two-level, add folded into consumers) + scatter
__global__ __launch_bounds__(256)
void scan_local_kernel(const int* __restrict__ counts, int* __restrict__ offsets,
                       int* __restrict__ bsum)
{
    __shared__ int lds4[4];
    int i = blockIdx.x * 256 + threadIdx.x;
    int v = (i < NN) ? counts[i] : 0;
    int total;
    int ex = block_excl_scan(v, lds4, &total);
    if (i < NN) offsets[i] = ex;
    if (threadIdx.x == 0) bsum[blockIdx.x] = total;
}

__global__ __launch_bounds__(256)
void scan_bsum_kernel(int* __restrict__ bsum)
{
    __shared__ int lds4[4];
    int t = threadIdx.x;
    int v = (t < SB) ? bsum[t] : 0;
    int total;
    int ex = block_excl_scan(v, lds4, &total);
    if (t < SB) bsum[t] = ex;
}

// one random 4B write per edge (src 16b | type 16b packed; N<65536, R<256)
__global__ __launch_bounds__(256)
void scatter_kernel(const int* __restrict__ ei, const int* __restrict__ et,
                    const int* __restrict__ offsets, const int* __restrict__ bsum,
                    int* __restrict__ fill, u32* __restrict__ dstorder)
{
    int e = blockIdx.x * 256 + threadIdx.x;
    if (e >= EE) return;
    int d = ei[EE + e];
    int pos = offsets[d] + bsum[d >> 8] + atomicAdd(&fill[d], 1);
    dstorder[pos] = (u32)ei[e] | ((u32)et[e] << 16);
}

// ---------------- fused per-node: logits + softmax (no-shift) + aggregate + bias + act
// one wave per dst node; 4 edge-groups of 16 lanes; lane owns 8 channels (c0=(lane&15)*8)
// ALL fp16-packed math; gathers via 32-bit element offsets (saddr form, less VALU).
__global__ __launch_bounds__(256)
void node_kernel(const u32* __restrict__ dstorder, const int* __restrict__ offsets,
                 const int* __restrict__ bsum,
                 const u16* __restrict__ xl, const u16* __restrict__ xr,
                 const u16* __restrict__ erel, const float* __restrict__ att,
                 const float* __restrict__ bias,
                 u16* __restrict__ xnext, float* __restrict__ outp, int is_last)
{
    int tid  = threadIdx.x;
    int node = blockIdx.x * 4 + (tid >> 6);
    int lane = tid & 63;
    if (node >= NN) return;
    int g  = lane >> 4;          // edge slot within quad
    int gl = lane & 15;          // channel set
    int c0 = gl * 8;
    int beg = offsets[node] + bsum[node >> 8];
    int end = (node == NN - 1) ? EE : offsets[node + 1] + bsum[(node + 1) >> 8];

    // per-node constants (packed fp16)
    h2 xrh[4], atth[4];
    {
        u32x4 xrv = *(const u32x4*)(xr + ((u32)node * DD + c0));
        #pragma unroll
        for (int q = 0; q < 4; q++) xrh[q] = u2h2(xrv[q]);
        #pragma unroll
        for (int q = 0; q < 4; q++) {
            float2 av = *(const float2*)&att[c0 + q * 2];
            atth[q] = (h2){(_Float16)av.x, (_Float16)av.y};
        }
    }
    const h2 c02 = (h2){(_Float16)0.2f, (_Float16)0.2f};

    float s = 0.f;
    h2 a2[4];
    #pragma unroll
    for (int q = 0; q < 4; q++) a2[q] = (h2){(_Float16)0.f, (_Float16)0.f};

    for (int base = beg; base < end; base += 4) {
        int es = base + g;
        bool valid = es < end;
        u32 st = valid ? dstorder[es] : 0;
        // 32-bit element offsets: src*128+c0 < 6.4M, typ*128+c0 < 51200
        u32 xoff = (st & 0xffffu) * DD + (u32)c0;
        u32 eoff = (st >> 16) * DD + (u32)c0;
        u32x4 xv = *(const u32x4*)(xl + xoff);
        u32x4 ev = *(const u32x4*)(erel + eoff);
        h2 xh[4];
        float p = 0.f;
        #pragma unroll
        for (int q = 0; q < 4; q++) {
            xh[q] = u2h2(xv[q]);
            h2 m = (xh[q] + xrh[q]) + u2h2(ev[q]);   // v_pk_add_f16 x2
            m = hmax2(m, m * c02);                   // leaky: pk_mul + pk_max
            p = hdot2(m, atth[q], p);                // v_dot2_f32_f16 (fp32 acc)
        }
        // per-head logit: reduce over the 4 lanes of this head (gl span of 4)
        p += __shfl_xor(p, 1, 64);
        p += __shfl_xor(p, 2, 64);
        // softmax without max-shift: logits are O(1); clamp guards inf
        float w = valid ? __expf(fminf(p, 60.f)) : 0.f;
        s += w;
        h2 wh = (h2){(_Float16)w, (_Float16)w};
        #pragma unroll
        for (int q = 0; q < 4; q++) a2[q] += wh * xh[q];   // v_pk_fma_f16
    }

    // cross-group reduction (groups processed disjoint edges) — fp32 for safety
    float a[8];
    #pragma unroll
    for (int q = 0; q < 4; q++) { a[q*2] = (float)a2[q].x; a[q*2+1] = (float)a2[q].y; }
    #pragma unroll
    for (int j = 0; j < 8; j++) {
        a[j] += __shfl_xor(a[j], 16, 64);
        a[j] += __shfl_xor(a[j], 32, 64);
    }
    s += __shfl_xor(s, 16, 64);
    s += __shfl_xor(s, 32, 64);

    if (lane < 16) {
        float rh = 1.f / fmaxf(s, 1e-30f);
        float4 b0 = *(const float4*)&bias[c0];
        float4 b1 = *(const float4*)&bias[c0 + 4];
        float bv[8] = {b0.x, b0.y, b0.z, b0.w, b1.x, b1.y, b1.z, b1.w};
        float v[8];
        #pragma unroll
        for (int j = 0; j < 8; j++) v[j] = a[j] * rh + bv[j];
        if (is_last) {
            float4* op = (float4*)(outp + ((u32)node * DD + c0));
            op[0] = make_float4(v[0], v[1], v[2], v[3]);
            op[1] = make_float4(v[4], v[5], v[6], v[7]);
        } else {
            u16 pk[8];
            #pragma unroll
            for (int j = 0; j < 8; j++) {
                float w2 = v[j] > 0.f ? v[j] : __expf(v[j]) - 1.f;   // elu
                pk[j] = f2h(w2);
            }
            *(half8*)(xnext + ((u32)node * DD + c0)) = *(half8*)pk;
        }
    }
}

extern "C" void kernel_launch(void* const* d_in, const int* in_sizes, int n_in,
                              void* d_out, int out_size, void* d_ws, size_t ws_size,
                              hipStream_t stream)
{
    const int*   entity        = (const int*)d_in[0];
    const int*   edge_index    = (const int*)d_in[1];
    const int*   edge_type     = (const int*)d_in[2];
    const float* node_features = (const float*)d_in[3];
    const float* rel_emb       = (const float*)d_in[4];
    const float* proj_w        = (const float*)d_in[5];
    const float* proj_b        = (const float*)d_in[6];
    const float* w_l           = (const float*)d_in[7];
    const float* b_l           = (const float*)d_in[8];
    const float* w_r           = (const float*)d_in[9];
    const float* b_r           = (const float*)d_in[10];
    const float* w_e           = (const float*)d_in[11];
    const float* att           = (const float*)d_in[12];
    const float* bias          = (const float*)d_in[13];

    // workspace (~42 MB), all fp16 tensors in u16 containers:
    u16*   xb      = (u16*)d_ws;                           // NN*DD (layer-0 output / layer-1 input)
    u16*   xl      = xb + (size_t)NN * DD;                 // NN*DD
    u16*   xr      = xl + (size_t)NN * DD;                 // NN*DD
    u16*   erel    = xr + (size_t)NN * DD;                 // LL*RR*DD
    u16*   wt      = erel + (size_t)LL * RR * DD;          // WTOT: [fusedL][fusedR][wl1][wr1]
    u32*   dstorder= (u32*)(wt + WTOT);                    // EE u32 (src|type, dst-order)
    int*   counts  = (int*)(dstorder + (size_t)EE);        // NN int
    int*   fill    = counts + NN;                          // NN int
    int*   offsets = fill + NN;                            // NN int (local scans)
    int*   bsum    = offsets + NN;                         // SB int
    float* fbias   = (float*)(bsum + SB);                  // 256 fp32 (folded layer-0 bias)

    // ---- prep: zero counts+fill, then fused hist | wconv | fold | biasfold | relproj
    hipMemsetAsync(counts, 0, (size_t)NN * 2 * sizeof(int), stream);
    prep_kernel<<<HB + WB + FB + 1 + RB, 256, 0, stream>>>(
        edge_index, counts, proj_w, w_l, w_r, wt, rel_emb, w_e, erel,
        proj_b, b_l, b_r, fbias);

    // ---- CSR: two-level scan + packed scatter (edges constant across layers)
    scan_local_kernel<<<SB, 256, 0, stream>>>(counts, offsets, bsum);
    scan_bsum_kernel<<<1, 256, 0, stream>>>(bsum);
    scatter_kernel<<<(EE + 255) / 256, 256, 0, stream>>>(
        edge_index, edge_type, offsets, bsum, fill, dstorder);

    const int GB2 = (NN + 63) / 64;

    // ---- layer 0: proj folded into xl/xr — single GEMM reads node_features once
    gemm8_kernel<false, true, PK><<<GB2, 512, 0, stream>>>(
        node_features, entity, FF, FF,
        wt, fbias, xl,
        wt + (size_t)128 * PK, fbias + DD, xr, NN);
    node_kernel<<<(NN + 3) / 4, 256, 0, stream>>>(
        dstorder, offsets, bsum, xl, xr, erel,
        att, bias, xb, (float*)d_out, 0);

    // ---- layer 1: dual-output GEMM reads xb once (B fully preloaded: K=128)
    gemm8_kernel<true, false, DD><<<GB2, 512, 0, stream>>>(
        xb, nullptr, DD, DD,
        wt + (size_t)2 * 128 * PK, b_l + DD, xl,
        wt + (size_t)2 * 128 * PK + 128 * 128, b_r + DD, xr, NN);
    node_kernel<<<(NN + 3) / 4, 256, 0, stream>>>(
        dstorder, offsets, bsum, xl, xr, erel + (size_t)RR * DD,
        att + DD, bias + DD, xb, (float*)d_out, 1);
}

// Round 6
// 318.496 us; speedup vs baseline: 1.0888x; 1.0116x over previous
//
#include <hip/hip_runtime.h>

#define NN 50000
#define FF 300
#define DD 128
#define HH 4
#define CC 32
#define EE 640000
#define RR 200
#define LL 2
#define SB ((NN + 255) / 256)     // scan blocks = 196
#define PK 320                    // proj K padded to multiple of 64
#define WCONV (2 * 128 * 128)     // layer-1 wl/wr transposed fp16
#define WTOT (2 * 128 * PK + WCONV)
#define HB ((EE + 255) / 256)     // hist blocks in prep (2500)
#define WB (WCONV / 256)          // wconv blocks (128)
#define FB PK                     // weight-fold blocks (320, 2 (lr,k) pairs each)
#define RB (LL * RR / 2)          // relproj blocks (200)
#define CVB ((NN * (PK / 8) + 255) / 256)   // fp16-convert blocks (7813)

typedef unsigned short u16;
typedef unsigned int u32;
typedef unsigned long long u64;
typedef _Float16 h2   __attribute__((ext_vector_type(2)));
typedef _Float16 half8 __attribute__((ext_vector_type(8)));  // MFMA A/B frag (4 VGPRs)
typedef __attribute__((ext_vector_type(4))) float floatx4;   // MFMA accumulator
typedef u32 u32x4 __attribute__((ext_vector_type(4)));       // 16B packed-half load

__device__ __forceinline__ u16 f2h(float f) {
    union { _Float16 h; u16 u; } v; v.h = (_Float16)f; return v.u;
}
__device__ __forceinline__ h2 u2h2(u32 p) {
    union { u32 u; h2 h; } v; v.u = p; return v.h;
}
__device__ __forceinline__ h2 hmax2(h2 a, h2 b) {
#if __has_builtin(__builtin_elementwise_max)
    return __builtin_elementwise_max(a, b);
#else
    h2 r; r.x = a.x > b.x ? a.x : b.x; r.y = a.y > b.y ? a.y : b.y; return r;
#endif
}
__device__ __forceinline__ float hdot2(h2 a, h2 b, float c) {
#if __has_builtin(__builtin_amdgcn_fdot2)
    return __builtin_amdgcn_fdot2(a, b, c, false);
#else
    return c + (float)a.x * (float)b.x + (float)a.y * (float)b.y;
#endif
}
// async global->LDS DMA, 16 B per lane; dest = lds + lane*16 (wave-uniform base)
__device__ __forceinline__ void glds16(const void* g, void* l) {
    using gp = const unsigned int __attribute__((address_space(1)))*;
    using lp = unsigned int __attribute__((address_space(3)))*;
    __builtin_amdgcn_global_load_lds((gp)(u64)g, (lp)(u64)l, 16, 0, 0);
}

// block-wide (256 threads) scan: returns exclusive prefix of v; *total = block sum
__device__ __forceinline__ int block_excl_scan(int v, int* lds4, int* total) {
    int lane = threadIdx.x & 63, wid = threadIdx.x >> 6;
    int x = v;
    #pragma unroll
    for (int off = 1; off < 64; off <<= 1) {
        int y = __shfl_up(x, off, 64);
        if (lane >= off) x += y;
    }
    if (lane == 63) lds4[wid] = x;
    __syncthreads();
    int add = 0;
    #pragma unroll
    for (int w = 0; w < 4; w++) add += (w < wid) ? lds4[w] : 0;
    *total = lds4[0] + lds4[1] + lds4[2] + lds4[3];
    return x + add - v;
}

// ---------------- fused prep: hist | layer1 wconv | layer0 fold | biasfold |
//                  relproj | node_features gather+fp16-convert (padded to PK)
__global__ __launch_bounds__(256)
void prep_kernel(const int* __restrict__ ei, int* __restrict__ counts,
                 const float* __restrict__ proj_w, const float* __restrict__ w_l,
                 const float* __restrict__ w_r, u16* __restrict__ wt,
                 const float* __restrict__ rel_emb, const float* __restrict__ w_e,
                 u16* __restrict__ erel, const float* __restrict__ proj_b,
                 const float* __restrict__ b_l, const float* __restrict__ b_r,
                 float* __restrict__ fbias, const int* __restrict__ entity,
                 const float* __restrict__ nf, u16* __restrict__ xh)
{
    __shared__ float rv[2][DD];
    int b = blockIdx.x, tid = threadIdx.x;
    if (b < HB) {
        // degree histogram
        int e = b * 256 + tid;
        if (e < EE) atomicAdd(&counts[ei[EE + e]], 1);
    } else if (b < HB + WB) {
        // layer-1 weights: fp32 [k][n] -> fp16 wt[n][k], segs [wl1][wr1]
        int i = (b - HB) * 256 + tid;        // < 32768
        int seg = i >> 14;                   // 0 = wl1, 1 = wr1
        int r = i & 16383;
        int n = r >> 7, k = r & 127;
        const float* src = (seg == 0 ? w_l : w_r) + (size_t)DD * DD;  // layer 1
        wt[2 * 128 * PK + i] = f2h(src[(size_t)k * DD + n]);
    } else if (b < HB + WB + FB) {
        // fused layer-0 weights: F[k][n] = sum_j Wp[k][j]*W{l,r}0[j][n],
        // stored transposed fp16: wt[lr*128*PK + n*PK + k]  (k>=FF -> 0 pad)
        int half = tid >> 7, d = tid & 127;
        int pp = (b - HB - WB) * 2 + half;   // 0..639 = (lr,k)
        int lr = pp / PK, k = pp - lr * PK;
        rv[half][d] = (k < FF) ? proj_w[(size_t)k * DD + d] : 0.f;
        __syncthreads();
        float acc = 0.f;
        if (k < FF) {
            const float* W = lr ? w_r : w_l;             // layer 0
            #pragma unroll 8
            for (int j = 0; j < DD; j++) acc += rv[half][j] * W[(size_t)j * DD + d];
        }
        wt[(size_t)lr * 128 * PK + (size_t)d * PK + k] = f2h(acc);
    } else if (b == HB + WB + FB) {
        // fused layer-0 bias: fb = b_{l,r}0 + proj_b @ W{l,r}0  (fp32)
        int half = tid >> 7, d = tid & 127;
        if (tid < DD) rv[0][tid] = proj_b[tid];
        __syncthreads();
        const float* W = half ? w_r : w_l;
        float acc = half ? b_r[d] : b_l[d];
        #pragma unroll 8
        for (int j = 0; j < DD; j++) acc += rv[0][j] * W[(size_t)j * DD + d];
        fbias[half * DD + d] = acc;
    } else if (b < HB + WB + FB + 1 + RB) {
        // erel[l*RR+r][d] = rel_emb[r,:] @ w_e[l][:,d]   (2 lr per block, fp16 out)
        int half = tid >> 7, d = tid & 127;
        int lr = (b - HB - WB - FB - 1) * 2 + half;
        int l = lr / RR, r = lr - l * RR;
        rv[half][d] = rel_emb[r * DD + d];
        __syncthreads();
        const float* W = w_e + (size_t)l * DD * DD;
        float acc = 0.f;
        #pragma unroll 8
        for (int k = 0; k < DD; k++) acc += rv[half][k] * W[k * DD + d];
        erel[(size_t)lr * DD + d] = f2h(acc);
    } else {
        // xh[row][0..319] = fp16(nf[entity[row]][0..299]), zero-pad to 320
        int ci = (b - (HB + WB + FB + 1 + RB)) * 256 + tid;   // 8-elem chunk id
        if (ci < NN * (PK / 8)) {
            int row = ci / (PK / 8);
            int col = (ci - row * (PK / 8)) * 8;
            int xrow = entity[row];
            const float* src = nf + (size_t)xrow * FF + col;
            u16 o[8];
            if (col + 8 <= FF) {
                float4 f0 = *(const float4*)src;
                float4 f1 = *(const float4*)(src + 4);
                o[0] = f2h(f0.x); o[1] = f2h(f0.y); o[2] = f2h(f0.z); o[3] = f2h(f0.w);
                o[4] = f2h(f1.x); o[5] = f2h(f1.y); o[6] = f2h(f1.z); o[7] = f2h(f1.w);
            } else {
                #pragma unroll
                for (int j = 0; j < 8; j++) o[j] = (col + j < FF) ? f2h(src[j]) : (u16)0;
            }
            *(half8*)(xh + (size_t)row * PK + col) = *(half8*)o;
        }
    }
}

// ---------------- dual-output MFMA fp16 GEMM, m97-style global_load_lds staging.
// Tile 64 rows x 256 cols (C1 cols 0-127 | C2 cols 0-127), 8 waves; wave owns 32
// cols = B rows [32w,32w+32). BK=64, single-buffered LDS (A 8KB + B 32KB = 40KB),
// 2 barriers/step. Staging = async DMA (5x glds16/thread/step): no VGPR round-trip,
// no f2h, no ds_write. Per-lane SOURCE addresses carry the XOR swizzle
// (chunk ^ ((row&7)<<4)) so the linear DMA yields conflict-free ds_read_b128
// (8-cy floor, all 32 banks busy; verified pattern m173/m201).
template<int K>
__global__ __launch_bounds__(512)
void gemm_gll_kernel(const u16* __restrict__ A,   // [M][K] fp16, K-padded
                     const u16* __restrict__ BT1, const float* __restrict__ bias1,
                     u16* __restrict__ C1,
                     const u16* __restrict__ BT2, const float* __restrict__ bias2,
                     u16* __restrict__ C2, int M)
{
    __shared__ u16 As[64 * 64];
    __shared__ u16 Bs[256 * 64];
    int tid  = threadIdx.x;
    int m0   = blockIdx.x * 64;
    int wave = tid >> 6, lane = tid & 63;
    int quad = lane >> 4, l16 = lane & 15;

    floatx4 acc[4][2];
    #pragma unroll
    for (int i = 0; i < 4; i++)
        #pragma unroll
        for (int j = 0; j < 2; j++) acc[i][j] = (floatx4){0.f, 0.f, 0.f, 0.f};

    // ---- staging source pointers (per lane, swizzled), advance 128 B per K-step
    int arl = wave * 8 + (lane >> 3);            // local A row this lane stages
    int arg = m0 + arl; if (arg >= M) arg = M - 1;
    const char* ap = (const char*)(A + (size_t)arg * K)
                   + (((lane & 7) << 4) ^ ((arl & 7) << 4));
    const char* bp[4];
    #pragma unroll
    for (int c = 0; c < 4; c++) {
        int rowB = wave * 32 + c * 8 + (lane >> 3);   // 0..255
        const u16* base = (rowB < 128) ? BT1 : BT2;
        int br = rowB & 127;
        bp[c] = (const char*)(base + (size_t)br * K)
              + (((lane & 7) << 4) ^ ((br & 7) << 4));
    }
    char* AsW = (char*)As;
    char* BsW = (char*)Bs;
    const char* AsR = (const char*)As;
    const char* BsR = (const char*)Bs;
    int axor = (l16 & 7) << 4;

    for (int kk = 0; kk < K; kk += 64) {
        // issue 5 DMA loads (1 A + 4 B), then barrier (compiler emits vmcnt(0))
        glds16(ap + kk * 2, AsW + wave * 1024);
        #pragma unroll
        for (int c = 0; c < 4; c++)
            glds16(bp[c] + kk * 2, BsW + (wave * 4 + c) * 1024);
        __syncthreads();
        #pragma unroll
        for (int s2 = 0; s2 < 2; s2++) {
            int cb = (s2 * 64 + quad * 16) ^ axor;
            half8 af[4], bf[2];
            #pragma unroll
            for (int i = 0; i < 4; i++)
                af[i] = *(const half8*)(AsR + (i * 16 + l16) * 128 + cb);
            #pragma unroll
            for (int j = 0; j < 2; j++)
                bf[j] = *(const half8*)(BsR + (wave * 32 + j * 16 + l16) * 128 + cb);
            #pragma unroll
            for (int i = 0; i < 4; i++) {
                acc[i][0] = __builtin_amdgcn_mfma_f32_16x16x32_f16(af[i], bf[0], acc[i][0], 0, 0, 0);
                acc[i][1] = __builtin_amdgcn_mfma_f32_16x16x32_f16(af[i], bf[1], acc[i][1], 0, 0, 0);
            }
        }
        __syncthreads();
    }

    // epilogue: C/D layout col=lane&15, row=quad*4+reg (m89; dtype-independent m121)
    u16* Cw = (wave < 4) ? C1 : C2;
    const float* bw = (wave < 4) ? bias1 : bias2;
    int cb0 = (wave & 3) * 32;
    #pragma unroll
    for (int i = 0; i < 4; i++) {
        #pragma unroll
        for (int rr = 0; rr < 4; rr++) {
            int row = m0 + i * 16 + quad * 4 + rr;
            if (row < M) {
                #pragma unroll
                for (int j = 0; j < 2; j++) {
                    int col = cb0 + j * 16 + l16;
                    Cw[(size_t)row * DD + col] = f2h(acc[i][j][rr] + bw[col]);
                }
            }
        }
    }
}

// ---------------- CSR scan (two-level, add folded into consumers) + scatter
__global__ __launch_bounds__(256)
void scan_local_kernel(const int* __restrict__ counts, int* __restrict__ offsets,
                       int* __restrict__ bsum)
{
    __shared__ int lds4[4];
    int i = blockIdx.x * 256 + threadIdx.x;
    int v = (i < NN) ? counts[i] : 0;
    int total;
    int ex = block_excl_scan(v, lds4, &total);
    if (i < NN) offsets[i] = ex;
    if (threadIdx.x == 0) bsum[blockIdx.x] = total;
}

__global__ __launch_bounds__(256)
void scan_bsum_kernel(int* __restrict__ bsum)
{
    __shared__ int lds4[4];
    int t = threadIdx.x;
    int v = (t < SB) ? bsum[t] : 0;
    int total;
    int ex = block_excl_scan(v, lds4, &total);
    if (t < SB) bsum[t] = ex;
}

// one random 4B write per edge (src 16b | type 16b packed; N<65536, R<256)
__global__ __launch_bounds__(256)
void scatter_kernel(const int* __restrict__ ei, const int* __restrict__ et,
                    const int* __restrict__ offsets, const int* __restrict__ bsum,
                    int* __restrict__ fill, u32* __restrict__ dstorder)
{
    int e = blockIdx.x * 256 + threadIdx.x;
    if (e >= EE) return;
    int d = ei[EE + e];
    int pos = offsets[d] + bsum[d >> 8] + atomicAdd(&fill[d], 1);
    dstorder[pos] = (u32)ei[e] | ((u32)et[e] << 16);
}

// ---------------- fused per-node: logits + softmax (no-shift) + aggregate + bias + act
// one wave per dst node; 4 edge-groups of 16 lanes; lane owns 8 channels (c0=(lane&15)*8)
// ALL fp16-packed math; gathers via 32-bit element offsets (saddr form, less VALU).
__global__ __launch_bounds__(256)
void node_kernel(const u32* __restrict__ dstorder, const int* __restrict__ offsets,
                 const int* __restrict__ bsum,
                 const u16* __restrict__ xl, const u16* __restrict__ xr,
                 const u16* __restrict__ erel, const float* __restrict__ att,
                 const float* __restrict__ bias,
                 u16* __restrict__ xnext, float* __restrict__ outp, int is_last)
{
    int tid  = threadIdx.x;
    int node = blockIdx.x * 4 + (tid >> 6);
    int lane = tid & 63;
    if (node >= NN) return;
    int g  = lane >> 4;          // edge slot within quad
    int gl = lane & 15;          // channel set
    int c0 = gl * 8;
    int beg = offsets[node] + bsum[node >> 8];
    int end = (node == NN - 1) ? EE : offsets[node + 1] + bsum[(node + 1) >> 8];

    // per-node constants (packed fp16)
    h2 xrh[4], atth[4];
    {
        u32x4 xrv = *(const u32x4*)(xr + ((u32)node * DD + c0));
        #pragma unroll
        for (int q = 0; q < 4; q++) xrh[q] = u2h2(xrv[q]);
        #pragma unroll
        for (int q = 0; q < 4; q++) {
            float2 av = *(const float2*)&att[c0 + q * 2];
            atth[q] = (h2){(_Float16)av.x, (_Float16)av.y};
        }
    }
    const h2 c02 = (h2){(_Float16)0.2f, (_Float16)0.2f};

    float s = 0.f;
    h2 a2[4];
    #pragma unroll
    for (int q = 0; q < 4; q++) a2[q] = (h2){(_Float16)0.f, (_Float16)0.f};

    for (int base = beg; base < end; base += 4) {
        int es = base + g;
        bool valid = es < end;
        u32 st = valid ? dstorder[es] : 0;
        // 32-bit element offsets: src*128+c0 < 6.4M, typ*128+c0 < 51200
        u32 xoff = (st & 0xffffu) * DD + (u32)c0;
        u32 eoff = (st >> 16) * DD + (u32)c0;
        u32x4 xv = *(const u32x4*)(xl + xoff);
        u32x4 ev = *(const u32x4*)(erel + eoff);
        h2 xh[4];
        float p = 0.f;
        #pragma unroll
        for (int q = 0; q < 4; q++) {
            xh[q] = u2h2(xv[q]);
            h2 m = (xh[q] + xrh[q]) + u2h2(ev[q]);   // v_pk_add_f16 x2
            m = hmax2(m, m * c02);                   // leaky: pk_mul + pk_max
            p = hdot2(m, atth[q], p);                // v_dot2_f32_f16 (fp32 acc)
        }
        // per-head logit: reduce over the 4 lanes of this head (gl span of 4)
        p += __shfl_xor(p, 1, 64);
        p += __shfl_xor(p, 2, 64);
        // softmax without max-shift: logits are O(1); clamp guards inf
        float w = valid ? __expf(fminf(p, 60.f)) : 0.f;
        s += w;
        h2 wh = (h2){(_Float16)w, (_Float16)w};
        #pragma unroll
        for (int q = 0; q < 4; q++) a2[q] += wh * xh[q];   // v_pk_fma_f16
    }

    // cross-group reduction (groups processed disjoint edges) — fp32 for safety
    float a[8];
    #pragma unroll
    for (int q = 0; q < 4; q++) { a[q*2] = (float)a2[q].x; a[q*2+1] = (float)a2[q].y; }
    #pragma unroll
    for (int j = 0; j < 8; j++) {
        a[j] += __shfl_xor(a[j], 16, 64);
        a[j] += __shfl_xor(a[j], 32, 64);
    }
    s += __shfl_xor(s, 16, 64);
    s += __shfl_xor(s, 32, 64);

    if (lane < 16) {
        float rh = 1.f / fmaxf(s, 1e-30f);
        float4 b0 = *(const float4*)&bias[c0];
        float4 b1 = *(const float4*)&bias[c0 + 4];
        float bv[8] = {b0.x, b0.y, b0.z, b0.w, b1.x, b1.y, b1.z, b1.w};
        float v[8];
        #pragma unroll
        for (int j = 0; j < 8; j++) v[j] = a[j] * rh + bv[j];
        if (is_last) {
            float4* op = (float4*)(outp + ((u32)node * DD + c0));
            op[0] = make_float4(v[0], v[1], v[2], v[3]);
            op[1] = make_float4(v[4], v[5], v[6], v[7]);
        } else {
            u16 pk[8];
            #pragma unroll
            for (int j = 0; j < 8; j++) {
                float w2 = v[j] > 0.f ? v[j] : __expf(v[j]) - 1.f;   // elu
                pk[j] = f2h(w2);
            }
            *(half8*)(xnext + ((u32)node * DD + c0)) = *(half8*)pk;
        }
    }
}

extern "C" void kernel_launch(void* const* d_in, const int* in_sizes, int n_in,
                              void* d_out, int out_size, void* d_ws, size_t ws_size,
                              hipStream_t stream)
{
    const int*   entity        = (const int*)d_in[0];
    const int*   edge_index    = (const int*)d_in[1];
    const int*   edge_type     = (const int*)d_in[2];
    const float* node_features = (const float*)d_in[3];
    const float* rel_emb       = (const float*)d_in[4];
    const float* proj_w        = (const float*)d_in[5];
    const float* proj_b        = (const float*)d_in[6];
    const float* w_l           = (const float*)d_in[7];
    const float* b_l           = (const float*)d_in[8];
    const float* w_r           = (const float*)d_in[9];
    const float* b_r           = (const float*)d_in[10];
    const float* w_e           = (const float*)d_in[11];
    const float* att           = (const float*)d_in[12];
    const float* bias          = (const float*)d_in[13];

    // workspace (~74 MB), all fp16 tensors in u16 containers:
    u16*   xb      = (u16*)d_ws;                           // NN*DD (layer-0 output / layer-1 input)
    u16*   xl      = xb + (size_t)NN * DD;                 // NN*DD
    u16*   xr      = xl + (size_t)NN * DD;                 // NN*DD
    u16*   erel    = xr + (size_t)NN * DD;                 // LL*RR*DD
    u16*   wt      = erel + (size_t)LL * RR * DD;          // WTOT: [fusedL][fusedR][wl1][wr1]
    u32*   dstorder= (u32*)(wt + WTOT);                    // EE u32 (src|type, dst-order)
    int*   counts  = (int*)(dstorder + (size_t)EE);        // NN int
    int*   fill    = counts + NN;                          // NN int
    int*   offsets = fill + NN;                            // NN int (local scans)
    int*   bsum    = offsets + NN;                         // SB int
    float* fbias   = (float*)(bsum + SB);                  // 256 fp32 (folded layer-0 bias)
    u16*   xh      = (u16*)(fbias + 2 * DD);               // NN*PK fp16 gathered features

    // ---- prep: zero counts+fill, then fused sections
    hipMemsetAsync(counts, 0, (size_t)NN * 2 * sizeof(int), stream);
    prep_kernel<<<HB + WB + FB + 1 + RB + CVB, 256, 0, stream>>>(
        edge_index, counts, proj_w, w_l, w_r, wt, rel_emb, w_e, erel,
        proj_b, b_l, b_r, fbias, entity, node_features, xh);

    // ---- CSR: two-level scan + packed scatter (edges constant across layers)
    scan_local_kernel<<<SB, 256, 0, stream>>>(counts, offsets, bsum);
    scan_bsum_kernel<<<1, 256, 0, stream>>>(bsum);
    scatter_kernel<<<(EE + 255) / 256, 256, 0, stream>>>(
        edge_index, edge_type, offsets, bsum, fill, dstorder);

    const int GB2 = (NN + 63) / 64;

    // ---- layer 0: proj folded into xl/xr — reads pre-gathered fp16 xh once
    gemm_gll_kernel<PK><<<GB2, 512, 0, stream>>>(
        xh, wt, fbias, xl,
        wt + (size_t)128 * PK, fbias + DD, xr, NN);
    node_kernel<<<(NN + 3) / 4, 256, 0, stream>>>(
        dstorder, offsets, bsum, xl, xr, erel,
        att, bias, xb, (float*)d_out, 0);

    // ---- layer 1: dual-output GEMM reads xb once
    gemm_gll_kernel<DD><<<GB2, 512, 0, stream>>>(
        xb, wt + (size_t)2 * 128 * PK, b_l + DD, xl,
        wt + (size_t)2 * 128 * PK + 128 * 128, b_r + DD, xr, NN);
    node_kernel<<<(NN + 3) / 4, 256, 0, stream>>>(
        dstorder, offsets, bsum, xl, xr, erel + (size_t)RR * DD,
        att + DD, bias + DD, xb, (float*)d_out, 1);
}